// Round 1
// baseline (61671.503 us; speedup 1.0000x reference)
//
#include <hip/hip_runtime.h>
#include <hip/hip_cooperative_groups.h>

namespace cg = cooperative_groups;

#define NB   128   // batch
#define NH   512   // hidden
#define NE   256   // embed
#define NK   256   // tags
#define NTE  256   // encoder length
#define NT   256   // decode steps
#define NBLK 256
#define NTHR 512
#define NWAVES 2048  // NBLK * NTHR/64

// ws offsets in floats
#define OFF_H      0        // hT   (512,128)
#define OFF_LOG    65536    // attn logits (256,128)
#define OFF_GH     98304    // ghT  (1536,128)
#define OFF_EM     294912   // emT  (256,128)
#define OFF_CTX    327680   // ctxT (1024,128)  (fallback path only)
#define OFF_X      458752   // xT   (512,128)
#define OFF_S      524288   // CRF shifted score (256,128)
#define OFF_PT     557056   // CRF p = exp(s - C) (256,128); reused as llh buf at end
#define OFF_EXPT   589824   // expT2[kc*256+j] = exp(trans[j,kc]) (256,256)
#define OFF_ET     655360   // eT (256,128) current embedding, transposed
#define OFF_EPART  688128   // epart[b*512+c] comb e-part (128,512)
#define OFF_M      753664   // Mbuf[2][128] lagged max
#define OFF_O      753920   // O[b] accumulated offset
#define OFF_NS     754048   // static numerator per b
#define OFF_NE2    754176   // emission numerator per b
#define OFF_ENCW   786432   // bf16 encW[t*65536 + b*512 + c], 16.7M ushorts (32MB)

struct Params {
  const int* dec; const int* tags; const float* enc; const float* emb;
  const float* aW; const float* ab; const float* cW; const float* cb;
  const float* wih; const float* whh; const float* bih; const float* bhh;
  const float* oW; const float* ob; const float* cs; const float* ce; const float* ct;
  float* ws; float* out; int encw;
};

__device__ __forceinline__ float bf2f(unsigned short u) {
  return __uint_as_float(((unsigned)u) << 16);
}
__device__ __forceinline__ unsigned short f2bf(float f) {
  unsigned u = __float_as_uint(f);
  unsigned r = (u + 0x7FFFu + ((u >> 16) & 1u)) >> 16;
  return (unsigned short)r;
}

// dot of weight row (contiguous) with activation stored (feat, B): a[k*NB + b]
__device__ __forceinline__ float dotKB(const float* __restrict__ w,
                                       const float* __restrict__ a,
                                       int len, int b) {
  float acc = 0.f;
  for (int k = 0; k < len; k += 4) {
    float4 wv = *reinterpret_cast<const float4*>(w + k);
    acc = fmaf(wv.x, a[(k + 0) * NB + b], acc);
    acc = fmaf(wv.y, a[(k + 1) * NB + b], acc);
    acc = fmaf(wv.z, a[(k + 2) * NB + b], acc);
    acc = fmaf(wv.w, a[(k + 3) * NB + b], acc);
  }
  return acc;
}

// ---------------- startup: init buffers, expT, static numerator, e for s=0
__global__ void __launch_bounds__(256) kInit(const int* __restrict__ dec,
                                             const int* __restrict__ tags,
                                             const float* __restrict__ emb,
                                             const float* __restrict__ cs,
                                             const float* __restrict__ ce,
                                             const float* __restrict__ ct,
                                             float* __restrict__ ws) {
  const int idx = blockIdx.x * 256 + threadIdx.x;  // 0..65535
  {
    const int kc = idx >> 8, j = idx & 255;
    (ws + OFF_EXPT)[idx] = __expf(ct[j * NK + kc]);
  }
  (ws + OFF_H)[idx] = 0.f;
  if (idx < 32768) {
    const int j = idx >> 7, b = idx & 127;
    const int tok = dec[b];
    (ws + OFF_ET)[j * NB + b] = emb[tok * NE + j];
  }
  if (idx < NB) {
    int prev = tags[idx];
    float acc = cs[prev];
    for (int t = 1; t < NT; ++t) {
      const int cur = tags[t * NB + idx];
      acc += ct[prev * NK + cur];
      prev = cur;
    }
    acc += ce[prev];
    (ws + OFF_NS)[idx] = acc;
    (ws + OFF_NE2)[idx] = 0.f;
    (ws + OFF_O)[idx] = 0.f;
  }
}

// ---------------- startup: encW[t,b,c] = sum_j enc[t,b,j] * comb_W[c, 256+j]  (bf16 out)
__global__ void __launch_bounds__(256) kEncW(const float* __restrict__ enc,
                                             const float* __restrict__ cW,
                                             unsigned short* __restrict__ encW) {
  __shared__ float wL[64 * 64];
  const int t = blockIdx.x >> 3, cblk = blockIdx.x & 7;
  const int tid = threadIdx.x;
  const int bg = tid & 31;   // owns b = bg*4 .. +3
  const int cg = tid >> 5;   // owns c = cblk*64 + cg*8 .. +7
  float acc[4][8];
#pragma unroll
  for (int i = 0; i < 4; ++i)
#pragma unroll
    for (int c = 0; c < 8; ++c) acc[i][c] = 0.f;
  const float* encB = enc + (size_t)t * (NB * 1024);
  for (int jt = 0; jt < 16; ++jt) {
    const int j0 = jt * 64;
    __syncthreads();
    for (int i = tid; i < 4096; i += 256) {
      const int cc = i >> 6, jj = i & 63;
      wL[cc * 64 + jj] = cW[(size_t)(cblk * 64 + cc) * 1280 + 256 + j0 + jj];
    }
    __syncthreads();
    for (int jj = 0; jj < 64; ++jj) {
      const float e0 = encB[(bg * 4 + 0) * 1024 + j0 + jj];
      const float e1 = encB[(bg * 4 + 1) * 1024 + j0 + jj];
      const float e2 = encB[(bg * 4 + 2) * 1024 + j0 + jj];
      const float e3 = encB[(bg * 4 + 3) * 1024 + j0 + jj];
#pragma unroll
      for (int c = 0; c < 8; ++c) {
        const float w = wL[(cg * 8 + c) * 64 + jj];
        acc[0][c] = fmaf(e0, w, acc[0][c]);
        acc[1][c] = fmaf(e1, w, acc[1][c]);
        acc[2][c] = fmaf(e2, w, acc[2][c]);
        acc[3][c] = fmaf(e3, w, acc[3][c]);
      }
    }
  }
  unsigned short* outB = encW + (size_t)t * 65536;
#pragma unroll
  for (int i = 0; i < 4; ++i)
    for (int c = 0; c < 8; ++c) {
      const int b = bg * 4 + i, cc = cblk * 64 + cg * 8 + c;
      outB[(size_t)b * 512 + cc] = f2bf(acc[i][c]);
    }
}

// ---------------- main persistent cooperative kernel
__global__ void __launch_bounds__(NTHR) maink(Params p) {
  cg::grid_group grid = cg::this_grid();
  float* const ws = p.ws;
  float* const hT = ws + OFF_H;
  float* const lgT = ws + OFF_LOG;
  float* const ghT = ws + OFF_GH;
  float* const emT = ws + OFF_EM;
  float* const ctxT = ws + OFF_CTX;
  float* const xT = ws + OFF_X;
  float* const sT = ws + OFF_S;
  float* const pT = ws + OFF_PT;
  float* const eXT = ws + OFF_EXPT;
  float* const eT = ws + OFF_ET;
  float* const ep = ws + OFF_EPART;
  float* const Mb = ws + OFF_M;
  float* const Ob = ws + OFF_O;
  float* const nS = ws + OFF_NS;
  float* const nE = ws + OFF_NE2;
  const unsigned short* const encW = (const unsigned short*)(ws + OFF_ENCW);

  const int tid = threadIdx.x;
  const int lane = tid & 63;
  const int gw = blockIdx.x * (NTHR / 64) + (tid >> 6);

  for (int s = 0; s <= NT; ++s) {
    // ================= Phase G1: everything that needs only h (and eT) =================
    {
      const int nA = (s < NT) ? 512 : 0;     // attn logits: 256 t x 2 halves
      const int nG = (s < NT) ? 3072 : 0;    // gh: 1536 x 2
      const int nEm = (s >= 1) ? 512 : 0;    // emissions for t = s-1: 256 x 2
      const int nEp = (p.encw && s < NT) ? 1024 : 0;  // comb e-part: 512 x 2
      const int tot = nA + nG + nEm + nEp;
      for (int tk = gw; tk < tot; tk += NWAVES) {
        int id = tk;
        if (id < nA) {
          const int t = id >> 1; const int b = ((id & 1) << 6) + lane;
          float acc = p.ab[t];
          acc += dotKB(p.aW + (size_t)t * 768, eT, 256, b);
          acc += dotKB(p.aW + (size_t)t * 768 + 256, hT, 512, b);
          lgT[t * NB + b] = acc;
          continue;
        }
        id -= nA;
        if (id < nG) {
          const int c = id >> 1; const int b = ((id & 1) << 6) + lane;
          ghT[c * NB + b] = p.bhh[c] + dotKB(p.whh + (size_t)c * 512, hT, 512, b);
          continue;
        }
        id -= nG;
        if (id < nEm) {
          const int k = id >> 1; const int b = ((id & 1) << 6) + lane;
          emT[k * NB + b] = p.ob[k] + dotKB(p.oW + (size_t)k * 512, hT, 512, b);
          continue;
        }
        id -= nEm;
        {
          const int c = id >> 1; const int b = ((id & 1) << 6) + lane;
          ep[b * 512 + c] = p.cb[c] + dotKB(p.cW + (size_t)c * 1280, eT, 256, b);
        }
      }
    }
    grid.sync();

    // ================= Phase P2: softmax + (x directly via encW | ctx) + CRF p =================
    {
      const int nX = (s < NT) ? (p.encw ? 512 : 1024) : 0;
      const int nP = (s >= 2) ? 16 : 0;
      const int tot = nX + nP;
      for (int tk = gw; tk < tot; tk += NWAVES) {
        if (tk < nX) {
          int b, seg;
          if (p.encw) { b = tk >> 2; seg = tk & 3; } else { b = tk >> 3; seg = tk & 7; }
          // softmax stats for row b (redundant per wave; cheap)
          const float l0 = lgT[(lane) * NB + b], l1 = lgT[(64 + lane) * NB + b];
          const float l2 = lgT[(128 + lane) * NB + b], l3 = lgT[(192 + lane) * NB + b];
          float m = fmaxf(fmaxf(l0, l1), fmaxf(l2, l3));
#pragma unroll
          for (int o = 32; o; o >>= 1) m = fmaxf(m, __shfl_xor(m, o));
          float sm = __expf(l0 - m) + __expf(l1 - m) + __expf(l2 - m) + __expf(l3 - m);
#pragma unroll
          for (int o = 32; o; o >>= 1) sm += __shfl_xor(sm, o);
          const float inv = 1.f / sm;
          if (p.encw) {
            const int c0 = seg * 128 + lane * 2;
            const unsigned short* ew = encW + (size_t)b * 512 + c0;
            float ax = 0.f, ay = 0.f;
            for (int t = 0; t < NTE; ++t) {
              const float pr = __expf(lgT[t * NB + b] - m);
              const ushort2 w2 = *reinterpret_cast<const ushort2*>(ew + (size_t)t * 65536);
              ax = fmaf(pr, bf2f(w2.x), ax);
              ay = fmaf(pr, bf2f(w2.y), ay);
            }
            const float xv0 = fmaxf(ep[b * 512 + c0] + ax * inv, 0.f);
            const float xv1 = fmaxf(ep[b * 512 + c0 + 1] + ay * inv, 0.f);
            xT[(c0) * NB + b] = xv0;
            xT[(c0 + 1) * NB + b] = xv1;
          } else {
            const int j0 = seg * 128 + lane * 2;
            const float* eb = p.enc + (size_t)b * 1024 + j0;
            float ax = 0.f, ay = 0.f;
            for (int t = 0; t < NTE; ++t) {
              const float pr = __expf(lgT[t * NB + b] - m);
              const float2 ev = *reinterpret_cast<const float2*>(eb + (size_t)t * 131072);
              ax = fmaf(pr, ev.x, ax);
              ay = fmaf(pr, ev.y, ay);
            }
            ctxT[(j0) * NB + b] = ax * inv;
            ctxT[(j0 + 1) * NB + b] = ay * inv;
          }
        } else {
          // CRF: p = exp(s~ - C), lagged max M
          const int w = tk - nX;
          const int ks = w >> 1; const int b = ((w & 1) << 6) + lane;
          const float C = (s == 2) ? 0.f : Mb[((s - 1) & 1) * NB + b];
          float mx = -1e30f;
          for (int k = 0; k < NK; ++k) mx = fmaxf(mx, sT[k * NB + b]);
          if (ks == 0) Mb[(s & 1) * NB + b] = mx;
          for (int k = ks * 32; k < ks * 32 + 32; ++k)
            pT[k * NB + b] = __expf(sT[k * NB + b] - C);
        }
      }
    }
    grid.sync();

    // ================= Phase P3x (fallback only): x from ctx, CRF update, misc =================
    if (!p.encw) {
      const int nXx = (s < NT) ? 1024 : 0;
      const int nC = (s >= 1) ? 512 : 0;
      const int nM = (s >= 1) ? 2 : 0;
      const int tot = nXx + nC + nM;
      for (int tk = gw; tk < tot; tk += NWAVES) {
        int id = tk;
        if (id < nXx) {
          const int c = id >> 1; const int b = ((id & 1) << 6) + lane;
          float acc = p.cb[c] + dotKB(p.cW + (size_t)c * 1280, eT, 256, b)
                    + dotKB(p.cW + (size_t)c * 1280 + 256, ctxT, 1024, b);
          xT[c * NB + b] = fmaxf(acc, 0.f);
          continue;
        }
        id -= nXx;
        if (id < nC) {
          const int kc = id >> 1; const int b = ((id & 1) << 6) + lane;
          if (s == 1) sT[kc * NB + b] = p.cs[kc] + emT[kc * NB + b];
          else {
            const float d = dotKB(eXT + (size_t)kc * 256, pT, 256, b);
            sT[kc * NB + b] = __logf(d) + emT[kc * NB + b];
          }
          continue;
        }
        id -= nC;
        {
          const int b = (id << 6) + lane;
          const int tag = p.tags[(s - 1) * NB + b];
          nE[b] += emT[tag * NB + b];
          if (s >= 2) {
            const float C = (s == 2) ? 0.f : Mb[((s - 1) & 1) * NB + b];
            Ob[b] += C;
          }
        }
      }
      grid.sync();
    }

    // ================= Phase P3r: GRU gates + h_new, next-e fill, (encw: CRF update, misc) =====
    {
      const bool doit = p.encw ? true : (s < NT);
      if (doit) {
        const int nH = (s < NT) ? 1024 : 0;
        const int nEt = (s < NT - 1) ? 128 : 0;
        const int nC = (p.encw && s >= 1) ? 512 : 0;
        const int nM = (p.encw && s >= 1) ? 2 : 0;
        const int tot = nH + nEt + nC + nM;
        for (int tk = gw; tk < tot; tk += NWAVES) {
          int id = tk;
          if (id < nH) {
            const int c = id >> 1; const int b = ((id & 1) << 6) + lane;
            const float gr = p.bih[c] + dotKB(p.wih + (size_t)c * 512, xT, 512, b);
            const float gz = p.bih[512 + c] + dotKB(p.wih + (size_t)(512 + c) * 512, xT, 512, b);
            const float gn = p.bih[1024 + c] + dotKB(p.wih + (size_t)(1024 + c) * 512, xT, 512, b);
            const float hr = ghT[c * NB + b], hz = ghT[(512 + c) * NB + b], hn = ghT[(1024 + c) * NB + b];
            const float r = 1.f / (1.f + __expf(-(gr + hr)));
            const float z = 1.f / (1.f + __expf(-(gz + hz)));
            const float n = tanhf(gn + r * hn);
            const float ho = hT[c * NB + b];
            hT[c * NB + b] = (1.f - z) * n + z * ho;
            continue;
          }
          id -= nH;
          if (id < nEt) {
            const int b = id;
            const int tok = p.tags[s * NB + b];  // input for step s+1 = output_tensor[s]
#pragma unroll
            for (int i = 0; i < 4; ++i) {
              const int j = (i << 6) + lane;
              eT[j * NB + b] = p.emb[tok * NE + j];
            }
            continue;
          }
          id -= nEt;
          if (id < nC) {
            const int kc = id >> 1; const int b = ((id & 1) << 6) + lane;
            if (s == 1) sT[kc * NB + b] = p.cs[kc] + emT[kc * NB + b];
            else {
              const float d = dotKB(eXT + (size_t)kc * 256, pT, 256, b);
              sT[kc * NB + b] = __logf(d) + emT[kc * NB + b];
            }
            continue;
          }
          id -= nC;
          {
            const int b = (id << 6) + lane;
            const int tag = p.tags[(s - 1) * NB + b];
            nE[b] += emT[tag * NB + b];
            if (s >= 2) {
              const float C = (s == 2) ? 0.f : Mb[((s - 1) & 1) * NB + b];
              Ob[b] += C;
            }
          }
        }
        grid.sync();
      }
    }
  }

  // ================= Final: denominator + mean llh (block 0) =================
  if (blockIdx.x == 0) {
    float* const llhB = pT;  // reuse
    if ((tid >> 6) < 2) {
      const int b = ((tid >> 6) << 6) + lane;
      float mx = -1e30f;
      for (int k = 0; k < NK; ++k) mx = fmaxf(mx, sT[k * NB + b] + p.ce[k]);
      float sum = 0.f;
      for (int k = 0; k < NK; ++k) sum += __expf(sT[k * NB + b] + p.ce[k] - mx);
      const float den = Ob[b] + mx + __logf(sum);
      llhB[b] = nS[b] + nE[b] - den;
    }
    __syncthreads();
    if ((tid >> 6) == 0) {
      float v = llhB[lane] + llhB[64 + lane];
#pragma unroll
      for (int o = 32; o; o >>= 1) v += __shfl_xor(v, o);
      if (lane == 0) p.out[0] = v * (1.f / 128.f);
    }
  }
}

extern "C" void kernel_launch(void* const* d_in, const int* in_sizes, int n_in,
                              void* d_out, int out_size, void* d_ws, size_t ws_size,
                              hipStream_t stream) {
  (void)in_sizes; (void)n_in; (void)out_size;
  Params p;
  p.dec = (const int*)d_in[0];
  p.tags = (const int*)d_in[1];
  p.enc = (const float*)d_in[2];
  p.emb = (const float*)d_in[3];
  p.aW = (const float*)d_in[4];
  p.ab = (const float*)d_in[5];
  p.cW = (const float*)d_in[6];
  p.cb = (const float*)d_in[7];
  p.wih = (const float*)d_in[8];
  p.whh = (const float*)d_in[9];
  p.bih = (const float*)d_in[10];
  p.bhh = (const float*)d_in[11];
  p.oW = (const float*)d_in[12];
  p.ob = (const float*)d_in[13];
  p.cs = (const float*)d_in[14];
  p.ce = (const float*)d_in[15];
  p.ct = (const float*)d_in[16];
  p.ws = (float*)d_ws;
  p.out = (float*)d_out;
  p.encw = (ws_size >= (40ull << 20)) ? 1 : 0;  // need ~36.7MB for encW path

  kInit<<<dim3(256), dim3(256), 0, stream>>>(p.dec, p.tags, p.emb, p.cs, p.ce, p.ct, p.ws);
  if (p.encw)
    kEncW<<<dim3(2048), dim3(256), 0, stream>>>(p.enc, p.cW,
                                                (unsigned short*)(p.ws + OFF_ENCW));
  void* args[] = { &p };
  hipLaunchCooperativeKernel((void*)maink, dim3(NBLK), dim3(NTHR), args, 0, stream);
}

// Round 2
// 61589.215 us; speedup vs baseline: 1.0013x; 1.0013x over previous
//
#include <hip/hip_runtime.h>
#include <hip/hip_cooperative_groups.h>

namespace cg = cooperative_groups;

#define NB   128   // batch
#define NH   512   // hidden
#define NE   256   // embed
#define NK   256   // tags
#define NTE  256   // encoder length
#define NT   256   // decode steps
#define NBLK 256
#define NTHR 512
#define NWAVES 2048  // NBLK * NTHR/64

// ws offsets in floats
#define OFF_H      0        // hT   (512,128)
#define OFF_LOG    65536    // attn logits (256,128)
#define OFF_GH     98304    // ghT  (1536,128)
#define OFF_EM     294912   // emT  (256,128)
#define OFF_CTX    327680   // ctxT (1024,128)  (fallback path only)
#define OFF_X      458752   // xT   (512,128)
#define OFF_S      524288   // CRF shifted score (256,128)
#define OFF_PT     557056   // CRF p = exp(s - C) (256,128); reused as llh buf at end
#define OFF_EXPT   589824   // expT2[kc*256+j] = exp(trans[j,kc]) (256,256)
#define OFF_ET     655360   // eT (256,128) current embedding, transposed
#define OFF_EPART  688128   // epart[b*512+c] comb e-part (128,512)
#define OFF_M      753664   // Mbuf[2][128] lagged max
#define OFF_O      753920   // O[b] accumulated offset
#define OFF_NS     754048   // static numerator per b
#define OFF_NE2    754176   // emission numerator per b
#define OFF_ENCW   786432   // bf16 encW[t*65536 + b*512 + c], 16.7M ushorts (32MB)

struct Params {
  const int* dec; const int* tags; const float* enc; const float* emb;
  const float* aW; const float* ab; const float* cW; const float* cb;
  const float* wih; const float* whh; const float* bih; const float* bhh;
  const float* oW; const float* ob; const float* cs; const float* ce; const float* ct;
  float* ws; float* out; int encw;
};

__device__ __forceinline__ float bf2f(unsigned short u) {
  return __uint_as_float(((unsigned)u) << 16);
}
__device__ __forceinline__ unsigned short f2bf(float f) {
  unsigned u = __float_as_uint(f);
  unsigned r = (u + 0x7FFFu + ((u >> 16) & 1u)) >> 16;
  return (unsigned short)r;
}

// dot of weight row (contiguous) with activation stored (feat, B): a[k*NB + b]
__device__ __forceinline__ float dotKB(const float* __restrict__ w,
                                       const float* __restrict__ a,
                                       int len, int b) {
  float acc = 0.f;
  for (int k = 0; k < len; k += 4) {
    float4 wv = *reinterpret_cast<const float4*>(w + k);
    acc = fmaf(wv.x, a[(k + 0) * NB + b], acc);
    acc = fmaf(wv.y, a[(k + 1) * NB + b], acc);
    acc = fmaf(wv.z, a[(k + 2) * NB + b], acc);
    acc = fmaf(wv.w, a[(k + 3) * NB + b], acc);
  }
  return acc;
}

// ---------------- startup: init buffers, expT, static numerator, e for s=0
__global__ void __launch_bounds__(256) kInit(const int* __restrict__ dec,
                                             const int* __restrict__ tags,
                                             const float* __restrict__ emb,
                                             const float* __restrict__ cs,
                                             const float* __restrict__ ce,
                                             const float* __restrict__ ct,
                                             float* __restrict__ ws) {
  const int idx = blockIdx.x * 256 + threadIdx.x;  // 0..65535
  {
    const int kc = idx >> 8, j = idx & 255;
    (ws + OFF_EXPT)[idx] = __expf(ct[j * NK + kc]);
  }
  (ws + OFF_H)[idx] = 0.f;
  if (idx < 32768) {
    const int j = idx >> 7, b = idx & 127;
    const int tok = dec[b];
    (ws + OFF_ET)[j * NB + b] = emb[tok * NE + j];
  }
  if (idx < NB) {
    int prev = tags[idx];
    float acc = cs[prev];
    for (int t = 1; t < NT; ++t) {
      const int cur = tags[t * NB + idx];
      acc += ct[prev * NK + cur];
      prev = cur;
    }
    acc += ce[prev];
    (ws + OFF_NS)[idx] = acc;
    (ws + OFF_NE2)[idx] = 0.f;
    (ws + OFF_O)[idx] = 0.f;
  }
}

// ---------------- startup: encW[t,b,c] = sum_j enc[t,b,j] * comb_W[c, 256+j]  (bf16 out)
__global__ void __launch_bounds__(256) kEncW(const float* __restrict__ enc,
                                             const float* __restrict__ cW,
                                             unsigned short* __restrict__ encW) {
  __shared__ float wL[64 * 64];
  const int t = blockIdx.x >> 3, cblk = blockIdx.x & 7;
  const int tid = threadIdx.x;
  const int bg = tid & 31;   // owns b = bg*4 .. +3
  const int cg = tid >> 5;   // owns c = cblk*64 + cg*8 .. +7
  float acc[4][8];
#pragma unroll
  for (int i = 0; i < 4; ++i)
#pragma unroll
    for (int c = 0; c < 8; ++c) acc[i][c] = 0.f;
  const float* encB = enc + (size_t)t * (NB * 1024);
  for (int jt = 0; jt < 16; ++jt) {
    const int j0 = jt * 64;
    __syncthreads();
    for (int i = tid; i < 4096; i += 256) {
      const int cc = i >> 6, jj = i & 63;
      wL[cc * 64 + jj] = cW[(size_t)(cblk * 64 + cc) * 1280 + 256 + j0 + jj];
    }
    __syncthreads();
    for (int jj = 0; jj < 64; ++jj) {
      const float e0 = encB[(bg * 4 + 0) * 1024 + j0 + jj];
      const float e1 = encB[(bg * 4 + 1) * 1024 + j0 + jj];
      const float e2 = encB[(bg * 4 + 2) * 1024 + j0 + jj];
      const float e3 = encB[(bg * 4 + 3) * 1024 + j0 + jj];
#pragma unroll
      for (int c = 0; c < 8; ++c) {
        const float w = wL[(cg * 8 + c) * 64 + jj];
        acc[0][c] = fmaf(e0, w, acc[0][c]);
        acc[1][c] = fmaf(e1, w, acc[1][c]);
        acc[2][c] = fmaf(e2, w, acc[2][c]);
        acc[3][c] = fmaf(e3, w, acc[3][c]);
      }
    }
  }
  unsigned short* outB = encW + (size_t)t * 65536;
#pragma unroll
  for (int i = 0; i < 4; ++i)
    for (int c = 0; c < 8; ++c) {
      const int b = bg * 4 + i, cc = cblk * 64 + cg * 8 + c;
      outB[(size_t)b * 512 + cc] = f2bf(acc[i][c]);
    }
}

// ---------------- main persistent cooperative kernel
__global__ void __launch_bounds__(NTHR) maink(Params p) {
  cg::grid_group grid = cg::this_grid();
  float* const ws = p.ws;
  float* const hT = ws + OFF_H;
  float* const lgT = ws + OFF_LOG;
  float* const ghT = ws + OFF_GH;
  float* const emT = ws + OFF_EM;
  float* const ctxT = ws + OFF_CTX;
  float* const xT = ws + OFF_X;
  float* const sT = ws + OFF_S;
  float* const pT = ws + OFF_PT;
  float* const eXT = ws + OFF_EXPT;
  float* const eT = ws + OFF_ET;
  float* const ep = ws + OFF_EPART;
  float* const Mb = ws + OFF_M;
  float* const Ob = ws + OFF_O;
  float* const nS = ws + OFF_NS;
  float* const nE = ws + OFF_NE2;
  const unsigned short* const encW = (const unsigned short*)(ws + OFF_ENCW);

  const int tid = threadIdx.x;
  const int lane = tid & 63;
  const int gw = blockIdx.x * (NTHR / 64) + (tid >> 6);

  for (int s = 0; s <= NT; ++s) {
    // ================= Phase G1: everything that needs only h (and eT) =================
    {
      const int nA = (s < NT) ? 512 : 0;     // attn logits: 256 t x 2 halves
      const int nG = (s < NT) ? 3072 : 0;    // gh: 1536 x 2
      const int nEm = (s >= 1) ? 512 : 0;    // emissions for t = s-1: 256 x 2
      const int nEp = (p.encw && s < NT) ? 1024 : 0;  // comb e-part: 512 x 2
      const int tot = nA + nG + nEm + nEp;
      for (int tk = gw; tk < tot; tk += NWAVES) {
        int id = tk;
        if (id < nA) {
          const int t = id >> 1; const int b = ((id & 1) << 6) + lane;
          float acc = p.ab[t];
          acc += dotKB(p.aW + (size_t)t * 768, eT, 256, b);
          acc += dotKB(p.aW + (size_t)t * 768 + 256, hT, 512, b);
          lgT[t * NB + b] = acc;
          continue;
        }
        id -= nA;
        if (id < nG) {
          const int c = id >> 1; const int b = ((id & 1) << 6) + lane;
          ghT[c * NB + b] = p.bhh[c] + dotKB(p.whh + (size_t)c * 512, hT, 512, b);
          continue;
        }
        id -= nG;
        if (id < nEm) {
          const int k = id >> 1; const int b = ((id & 1) << 6) + lane;
          emT[k * NB + b] = p.ob[k] + dotKB(p.oW + (size_t)k * 512, hT, 512, b);
          continue;
        }
        id -= nEm;
        {
          const int c = id >> 1; const int b = ((id & 1) << 6) + lane;
          ep[b * 512 + c] = p.cb[c] + dotKB(p.cW + (size_t)c * 1280, eT, 256, b);
        }
      }
    }
    grid.sync();

    // ================= Phase P2: softmax + (x directly via encW | ctx) + CRF p =================
    {
      const int nX = (s < NT) ? (p.encw ? 512 : 1024) : 0;
      const int nP = (s >= 2) ? 16 : 0;
      const int tot = nX + nP;
      for (int tk = gw; tk < tot; tk += NWAVES) {
        if (tk < nX) {
          int b, seg;
          if (p.encw) { b = tk >> 2; seg = tk & 3; } else { b = tk >> 3; seg = tk & 7; }
          // softmax stats for row b (redundant per wave; cheap)
          const float l0 = lgT[(lane) * NB + b], l1 = lgT[(64 + lane) * NB + b];
          const float l2 = lgT[(128 + lane) * NB + b], l3 = lgT[(192 + lane) * NB + b];
          float m = fmaxf(fmaxf(l0, l1), fmaxf(l2, l3));
#pragma unroll
          for (int o = 32; o; o >>= 1) m = fmaxf(m, __shfl_xor(m, o));
          float sm = __expf(l0 - m) + __expf(l1 - m) + __expf(l2 - m) + __expf(l3 - m);
#pragma unroll
          for (int o = 32; o; o >>= 1) sm += __shfl_xor(sm, o);
          const float inv = 1.f / sm;
          if (p.encw) {
            const int c0 = seg * 128 + lane * 2;
            const unsigned short* ew = encW + (size_t)b * 512 + c0;
            float ax = 0.f, ay = 0.f;
            for (int t = 0; t < NTE; ++t) {
              const float pr = __expf(lgT[t * NB + b] - m);
              const ushort2 w2 = *reinterpret_cast<const ushort2*>(ew + (size_t)t * 65536);
              ax = fmaf(pr, bf2f(w2.x), ax);
              ay = fmaf(pr, bf2f(w2.y), ay);
            }
            const float xv0 = fmaxf(ep[b * 512 + c0] + ax * inv, 0.f);
            const float xv1 = fmaxf(ep[b * 512 + c0 + 1] + ay * inv, 0.f);
            xT[(c0) * NB + b] = xv0;
            xT[(c0 + 1) * NB + b] = xv1;
          } else {
            const int j0 = seg * 128 + lane * 2;
            const float* eb = p.enc + (size_t)b * 1024 + j0;
            float ax = 0.f, ay = 0.f;
            for (int t = 0; t < NTE; ++t) {
              const float pr = __expf(lgT[t * NB + b] - m);
              const float2 ev = *reinterpret_cast<const float2*>(eb + (size_t)t * 131072);
              ax = fmaf(pr, ev.x, ax);
              ay = fmaf(pr, ev.y, ay);
            }
            ctxT[(j0) * NB + b] = ax * inv;
            ctxT[(j0 + 1) * NB + b] = ay * inv;
          }
        } else {
          // CRF: p = exp(s~ - C), lagged max M
          const int w = tk - nX;
          const int ks = w >> 1; const int b = ((w & 1) << 6) + lane;
          const float C = (s == 2) ? 0.f : Mb[((s - 1) & 1) * NB + b];
          float mx = -1e30f;
          for (int k = 0; k < NK; ++k) mx = fmaxf(mx, sT[k * NB + b]);
          if (ks == 0) Mb[(s & 1) * NB + b] = mx;
          for (int k = ks * 32; k < ks * 32 + 32; ++k)
            pT[k * NB + b] = __expf(sT[k * NB + b] - C);
        }
      }
    }
    grid.sync();

    // ================= Phase P3x (fallback only): x from ctx, CRF update, misc =================
    if (!p.encw) {
      const int nXx = (s < NT) ? 1024 : 0;
      const int nC = (s >= 1) ? 512 : 0;
      const int nM = (s >= 1) ? 2 : 0;
      const int tot = nXx + nC + nM;
      for (int tk = gw; tk < tot; tk += NWAVES) {
        int id = tk;
        if (id < nXx) {
          const int c = id >> 1; const int b = ((id & 1) << 6) + lane;
          float acc = p.cb[c] + dotKB(p.cW + (size_t)c * 1280, eT, 256, b)
                    + dotKB(p.cW + (size_t)c * 1280 + 256, ctxT, 1024, b);
          xT[c * NB + b] = fmaxf(acc, 0.f);
          continue;
        }
        id -= nXx;
        if (id < nC) {
          const int kc = id >> 1; const int b = ((id & 1) << 6) + lane;
          if (s == 1) sT[kc * NB + b] = p.cs[kc] + emT[kc * NB + b];
          else {
            const float d = dotKB(eXT + (size_t)kc * 256, pT, 256, b);
            sT[kc * NB + b] = __logf(d) + emT[kc * NB + b];
          }
          continue;
        }
        id -= nC;
        {
          const int b = (id << 6) + lane;
          const int tag = p.tags[(s - 1) * NB + b];
          nE[b] += emT[tag * NB + b];
          if (s >= 2) {
            const float C = (s == 2) ? 0.f : Mb[((s - 1) & 1) * NB + b];
            Ob[b] += C;
          }
        }
      }
      grid.sync();
    }

    // ================= Phase P3r: GRU gates + h_new, next-e fill, (encw: CRF update, misc) =====
    {
      const bool doit = p.encw ? true : (s < NT);
      if (doit) {
        const int nH = (s < NT) ? 1024 : 0;
        const int nEt = (s < NT - 1) ? 128 : 0;
        const int nC = (p.encw && s >= 1) ? 512 : 0;
        const int nM = (p.encw && s >= 1) ? 2 : 0;
        const int tot = nH + nEt + nC + nM;
        for (int tk = gw; tk < tot; tk += NWAVES) {
          int id = tk;
          if (id < nH) {
            const int c = id >> 1; const int b = ((id & 1) << 6) + lane;
            const float gr = p.bih[c] + dotKB(p.wih + (size_t)c * 512, xT, 512, b);
            const float gz = p.bih[512 + c] + dotKB(p.wih + (size_t)(512 + c) * 512, xT, 512, b);
            const float gn = p.bih[1024 + c] + dotKB(p.wih + (size_t)(1024 + c) * 512, xT, 512, b);
            const float hr = ghT[c * NB + b], hz = ghT[(512 + c) * NB + b], hn = ghT[(1024 + c) * NB + b];
            const float r = 1.f / (1.f + __expf(-(gr + hr)));
            const float z = 1.f / (1.f + __expf(-(gz + hz)));
            const float n = tanhf(gn + r * hn);
            const float ho = hT[c * NB + b];
            hT[c * NB + b] = (1.f - z) * n + z * ho;
            continue;
          }
          id -= nH;
          if (id < nEt) {
            const int b = id;
            const int tok = p.tags[s * NB + b];  // input for step s+1 = output_tensor[s]
#pragma unroll
            for (int i = 0; i < 4; ++i) {
              const int j = (i << 6) + lane;
              eT[j * NB + b] = p.emb[tok * NE + j];
            }
            continue;
          }
          id -= nEt;
          if (id < nC) {
            const int kc = id >> 1; const int b = ((id & 1) << 6) + lane;
            if (s == 1) sT[kc * NB + b] = p.cs[kc] + emT[kc * NB + b];
            else {
              const float d = dotKB(eXT + (size_t)kc * 256, pT, 256, b);
              sT[kc * NB + b] = __logf(d) + emT[kc * NB + b];
            }
            continue;
          }
          id -= nC;
          {
            const int b = (id << 6) + lane;
            const int tag = p.tags[(s - 1) * NB + b];
            nE[b] += emT[tag * NB + b];
            if (s >= 2) {
              const float C = (s == 2) ? 0.f : Mb[((s - 1) & 1) * NB + b];
              Ob[b] += C;
            }
          }
        }
        grid.sync();
      }
    }
  }

  // ================= Final: denominator + mean llh (block 0) =================
  if (blockIdx.x == 0) {
    float* const llhB = pT;  // reuse
    if ((tid >> 6) < 2) {
      const int b = ((tid >> 6) << 6) + lane;
      float mx = -1e30f;
      for (int k = 0; k < NK; ++k) mx = fmaxf(mx, sT[k * NB + b] + p.ce[k]);
      float sum = 0.f;
      for (int k = 0; k < NK; ++k) sum += __expf(sT[k * NB + b] + p.ce[k] - mx);
      const float den = Ob[b] + mx + __logf(sum);
      llhB[b] = nS[b] + nE[b] - den;
    }
    __syncthreads();
    if ((tid >> 6) == 0) {
      float v = llhB[lane] + llhB[64 + lane];
#pragma unroll
      for (int o = 32; o; o >>= 1) v += __shfl_xor(v, o);
      if (lane == 0) p.out[0] = v * (1.f / 128.f);
    }
  }
}

extern "C" void kernel_launch(void* const* d_in, const int* in_sizes, int n_in,
                              void* d_out, int out_size, void* d_ws, size_t ws_size,
                              hipStream_t stream) {
  (void)in_sizes; (void)n_in; (void)out_size;
  Params p;
  p.dec = (const int*)d_in[0];
  p.tags = (const int*)d_in[1];
  p.enc = (const float*)d_in[2];
  p.emb = (const float*)d_in[3];
  p.aW = (const float*)d_in[4];
  p.ab = (const float*)d_in[5];
  p.cW = (const float*)d_in[6];
  p.cb = (const float*)d_in[7];
  p.wih = (const float*)d_in[8];
  p.whh = (const float*)d_in[9];
  p.bih = (const float*)d_in[10];
  p.bhh = (const float*)d_in[11];
  p.oW = (const float*)d_in[12];
  p.ob = (const float*)d_in[13];
  p.cs = (const float*)d_in[14];
  p.ce = (const float*)d_in[15];
  p.ct = (const float*)d_in[16];
  p.ws = (float*)d_ws;
  p.out = (float*)d_out;
  p.encw = (ws_size >= (40ull << 20)) ? 1 : 0;  // need ~36.7MB for encW path

  kInit<<<dim3(256), dim3(256), 0, stream>>>(p.dec, p.tags, p.emb, p.cs, p.ce, p.ct, p.ws);
  if (p.encw)
    kEncW<<<dim3(2048), dim3(256), 0, stream>>>(p.enc, p.cW,
                                                (unsigned short*)(p.ws + OFF_ENCW));
  void* args[] = { &p };
  hipLaunchCooperativeKernel((void*)maink, dim3(NBLK), dim3(NTHR), args, 0, stream);
}

// Round 3
// 52328.333 us; speedup vs baseline: 1.1785x; 1.1770x over previous
//
#include <hip/hip_runtime.h>

// Round 3: zero-sync batch-parallel MFMA rewrite.
// 32 blocks x 512 threads; block owns 4 batch elems, runs all 256 steps + CRF locally.
// All big GEMMs on mfma_f32_16x16x32_bf16; weights pre-converted to bf16 in ws.

typedef unsigned short u16;
typedef unsigned int u32;
typedef __attribute__((ext_vector_type(8))) short short8;
typedef __attribute__((ext_vector_type(4))) short short4v;
typedef __attribute__((ext_vector_type(4))) float f32x4;

#define MFMA16(a, b, c) __builtin_amdgcn_mfma_f32_16x16x32_bf16((a), (b), (c), 0, 0, 0)

// ws layout: u16 element offsets
#define O16_ENC 0u          // encW bf16 [256 t][128 b][512 c]
#define O16_WIH 16777216u   // [1536][512]
#define O16_WHH 17563648u   // [1536][512]
#define O16_AW 18350080u    // [256][768] (cols 0-255 e, 256-767 h)
#define O16_OW 18546688u    // [256][512]
#define O16_CWE 18677760u   // [512][256] comb_W e-part
#define O16_EXPT 18808832u  // [256][256]  expT2[kn][k] = exp(trans[k][kn])
// float offsets
#define OF_NS 9437184u
#define OF_LLH 9437312u

__device__ __forceinline__ float bf2f(u16 u) { return __uint_as_float(((u32)u) << 16); }
__device__ __forceinline__ u16 f2bf(float f) {
  u32 u = __float_as_uint(f);
  return (u16)((u + 0x7FFFu + ((u >> 16) & 1u)) >> 16);
}

// A fragment: lane&15 = row, lane>>4 = k-subgroup of 8 (16B contiguous)
__device__ __forceinline__ short8 ldA(const u16* __restrict__ W, int K, int row, int k0, int kg) {
  return *reinterpret_cast<const short8*>(W + (size_t)row * K + (k0 + (kg << 3)));
}
// B fragment from b-major LDS tile (row stride RB bytes), XOR-swizzled by ((b&7)<<4)
__device__ __forceinline__ short8 ldB(const char* base, int RB, int k0, int bq, int kg) {
  const int off = (bq * RB + ((k0 + (kg << 3)) << 1)) ^ ((bq & 7) << 4);
  return *reinterpret_cast<const short8*>(base + off);
}

// ---------------- weight convert to bf16 (2,097,152 elems exactly) ----------------
__global__ void __launch_bounds__(256) kPrep(const float* __restrict__ wih,
                                             const float* __restrict__ whh,
                                             const float* __restrict__ aW,
                                             const float* __restrict__ oW,
                                             const float* __restrict__ cW,
                                             const float* __restrict__ ct,
                                             float* __restrict__ ws) {
  u16* W16 = (u16*)ws;
  const u32 idx = blockIdx.x * 256 + threadIdx.x;
  if (idx < 786432u) {
    W16[O16_WIH + idx] = f2bf(wih[idx]);
  } else if (idx < 1572864u) {
    const u32 i2 = idx - 786432u;
    W16[O16_WHH + i2] = f2bf(whh[i2]);
  } else if (idx < 1769472u) {
    const u32 i2 = idx - 1572864u;
    W16[O16_AW + i2] = f2bf(aW[i2]);
  } else if (idx < 1900544u) {
    const u32 i2 = idx - 1769472u;
    W16[O16_OW + i2] = f2bf(oW[i2]);
  } else if (idx < 2031616u) {
    const u32 i2 = idx - 1900544u;
    const u32 r = i2 >> 8, j = i2 & 255u;
    W16[O16_CWE + i2] = f2bf(cW[(size_t)r * 1280 + j]);
  } else {
    const u32 i2 = idx - 2031616u;
    const u32 kn = i2 >> 8, k = i2 & 255u;
    W16[O16_EXPT + i2] = f2bf(__expf(ct[k * 256 + kn]));
  }
}

// ---------------- static numerator per b ----------------
__global__ void kNS(const int* __restrict__ tags, const float* __restrict__ cs,
                    const float* __restrict__ ce, const float* __restrict__ ct,
                    float* __restrict__ ws) {
  const int b = threadIdx.x;  // 128
  int prev = tags[b];
  float acc = cs[prev];
  for (int t = 1; t < 256; ++t) {
    const int cur = tags[t * 128 + b];
    acc += ct[prev * 256 + cur];
    prev = cur;
  }
  ws[OF_NS + b] = acc + ce[prev];
}

// ---------------- encW[t,b,c] = sum_j enc[t,b,j] * comb_W[c, 256+j] (bf16) ----------------
__global__ void __launch_bounds__(256) kEncW(const float* __restrict__ enc,
                                             const float* __restrict__ cW,
                                             u16* __restrict__ encW) {
  __shared__ float wL[64 * 64];
  const int t = blockIdx.x >> 3, cblk = blockIdx.x & 7;
  const int tid = threadIdx.x;
  const int bg = tid & 31;
  const int cg = tid >> 5;
  float acc[4][8];
#pragma unroll
  for (int i = 0; i < 4; ++i)
#pragma unroll
    for (int c = 0; c < 8; ++c) acc[i][c] = 0.f;
  const float* encB = enc + (size_t)t * (128 * 1024);
  for (int jt = 0; jt < 16; ++jt) {
    const int j0 = jt * 64;
    __syncthreads();
    for (int i = tid; i < 4096; i += 256) {
      const int cc = i >> 6, jj = i & 63;
      wL[cc * 64 + jj] = cW[(size_t)(cblk * 64 + cc) * 1280 + 256 + j0 + jj];
    }
    __syncthreads();
    for (int jj = 0; jj < 64; ++jj) {
      const float e0 = encB[(bg * 4 + 0) * 1024 + j0 + jj];
      const float e1 = encB[(bg * 4 + 1) * 1024 + j0 + jj];
      const float e2 = encB[(bg * 4 + 2) * 1024 + j0 + jj];
      const float e3 = encB[(bg * 4 + 3) * 1024 + j0 + jj];
#pragma unroll
      for (int c = 0; c < 8; ++c) {
        const float wv = wL[(cg * 8 + c) * 64 + jj];
        acc[0][c] = fmaf(e0, wv, acc[0][c]);
        acc[1][c] = fmaf(e1, wv, acc[1][c]);
        acc[2][c] = fmaf(e2, wv, acc[2][c]);
        acc[3][c] = fmaf(e3, wv, acc[3][c]);
      }
    }
  }
  u16* outB = encW + (size_t)t * 65536;
#pragma unroll
  for (int i = 0; i < 4; ++i)
    for (int c = 0; c < 8; ++c) {
      const int b = bg * 4 + i, cc = cblk * 64 + cg * 8 + c;
      outB[(size_t)b * 512 + cc] = f2bf(acc[i][c]);
    }
}

// ---------------- main per-batch-group kernel ----------------
__global__ void __launch_bounds__(512, 2) maink(
    const int* __restrict__ dec, const int* __restrict__ tags,
    const float* __restrict__ emb, const float* __restrict__ ab,
    const float* __restrict__ cb, const float* __restrict__ bih,
    const float* __restrict__ bhh, const float* __restrict__ ob,
    const float* __restrict__ cs, const float* __restrict__ ce,
    float* __restrict__ ws) {
  __shared__ char sm[58624];
  char* const SH = sm;           // h bf16 [16][512]   (b-major, swizzled)
  char* const SE = sm + 16384;   // e bf16 [16][256]
  char* const SP = sm + 24576;   // pr f32 [16][256] then x bf16 [16][512] (same 1KB/row)
  char* const SX = sm + 40960;   // ep bf16 [16][512]; later p bf16 [16][256] (1KB rows)
  float* const red = (float*)(sm + 57344);   // [8][16]
  float* const red2 = (float*)(sm + 57856);  // [8][16]
  float* const nE2 = (float*)(sm + 58368);   // [16]
  float* const O16 = (float*)(sm + 58432);   // [16]

  const u16* const W16 = (const u16*)ws;
  const u16* const WIH = W16 + O16_WIH;
  const u16* const WHH = W16 + O16_WHH;
  const u16* const WAW = W16 + O16_AW;
  const u16* const WOW = W16 + O16_OW;
  const u16* const WCE = W16 + O16_CWE;
  const u16* const WXT = W16 + O16_EXPT;

  const int tid = threadIdx.x;
  const int w = tid >> 6, lane = tid & 63;
  const int bq = lane & 15, kg = lane >> 4;
  const int bg0 = blockIdx.x * 4;
  const bool bval = (bq < 4);
  const int swb = (bq & 7) << 4;

  f32x4 sr0, sr1;  // persistent CRF scores (k-tiles 2w, 2w+1)
  sr0 = (f32x4){0.f, 0.f, 0.f, 0.f};
  sr1 = sr0;

  // P0: zero all LDS, stage e for step 0
  for (int i = tid; i < 14656; i += 512) ((u32*)sm)[i] = 0u;
  __syncthreads();
  if (w < 4) {
    const int tok = dec[bg0 + w];
    const f32x4 ev = *(const f32x4*)(emb + (size_t)tok * 256 + lane * 4);
    short4v ee;
    ee[0] = (short)f2bf(ev[0]); ee[1] = (short)f2bf(ev[1]);
    ee[2] = (short)f2bf(ev[2]); ee[3] = (short)f2bf(ev[3]);
    *(short4v*)(SE + ((w * 512 + lane * 8) ^ ((w & 7) << 4))) = ee;
  }
  __syncthreads();

  for (int s = 0; s < 256; ++s) {
    // ========== P1a: e-based GEMMs: logits e-part + ep ==========
    f32x4 lg0, lg1, epa[4];
#pragma unroll
    for (int r = 0; r < 4; ++r) {
      lg0[r] = ab[w * 32 + kg * 4 + r];
      lg1[r] = ab[w * 32 + 16 + kg * 4 + r];
    }
#pragma unroll
    for (int j = 0; j < 4; ++j)
#pragma unroll
      for (int r = 0; r < 4; ++r) epa[j][r] = cb[(4 * w + j) * 16 + kg * 4 + r];
#pragma unroll 2
    for (int kt = 0; kt < 8; ++kt) {
      const short8 bb = ldB(SE, 512, kt * 32, bq, kg);
      lg0 = MFMA16(ldA(WAW, 768, w * 32 + bq, kt * 32, kg), bb, lg0);
      lg1 = MFMA16(ldA(WAW, 768, w * 32 + 16 + bq, kt * 32, kg), bb, lg1);
#pragma unroll
      for (int j = 0; j < 4; ++j)
        epa[j] = MFMA16(ldA(WCE, 256, (4 * w + j) * 16 + bq, kt * 32, kg), bb, epa[j]);
    }
    if (bval) {
#pragma unroll
      for (int j = 0; j < 4; ++j)
#pragma unroll
        for (int r = 0; r < 4; ++r) {
          const int c = (4 * w + j) * 16 + kg * 4 + r;
          *(u16*)(SX + ((bq * 1024 + c * 2) ^ swb)) = f2bf(epa[j][r]);
        }
    }

    // ========== P1b: h-based GEMMs: logits h-part + gh (R,Z,HN) ==========
    f32x4 R[4], Z[4], HN[4];
#pragma unroll
    for (int j = 0; j < 4; ++j)
#pragma unroll
      for (int r = 0; r < 4; ++r) {
        const int c = (4 * w + j) * 16 + kg * 4 + r;
        R[j][r] = bih[c] + bhh[c];
        Z[j][r] = bih[512 + c] + bhh[512 + c];
        HN[j][r] = bhh[1024 + c];
      }
#pragma unroll 1
    for (int kt = 0; kt < 16; ++kt) {
      const short8 bb = ldB(SH, 1024, kt * 32, bq, kg);
      lg0 = MFMA16(ldA(WAW + 256, 768, w * 32 + bq, kt * 32, kg), bb, lg0);
      lg1 = MFMA16(ldA(WAW + 256, 768, w * 32 + 16 + bq, kt * 32, kg), bb, lg1);
#pragma unroll
      for (int j = 0; j < 4; ++j) {
        R[j] = MFMA16(ldA(WHH, 512, (4 * w + j) * 16 + bq, kt * 32, kg), bb, R[j]);
        Z[j] = MFMA16(ldA(WHH, 512, 512 + (4 * w + j) * 16 + bq, kt * 32, kg), bb, Z[j]);
        HN[j] = MFMA16(ldA(WHH, 512, 1024 + (4 * w + j) * 16 + bq, kt * 32, kg), bb, HN[j]);
      }
    }

    // ========== softmax over t (registers + 2 LDS reductions) ==========
    {
      float pm = lg0[0];
#pragma unroll
      for (int r = 1; r < 4; ++r) pm = fmaxf(pm, lg0[r]);
#pragma unroll
      for (int r = 0; r < 4; ++r) pm = fmaxf(pm, lg1[r]);
      pm = fmaxf(pm, __shfl_xor(pm, 16));
      pm = fmaxf(pm, __shfl_xor(pm, 32));
      if (lane < 16) red[w * 16 + lane] = pm;
      __syncthreads();
      float mB = red[bq];
#pragma unroll
      for (int q = 1; q < 8; ++q) mB = fmaxf(mB, red[q * 16 + bq]);
      float sm1 = 0.f;
      float pr0[4], pr1[4];
#pragma unroll
      for (int r = 0; r < 4; ++r) {
        pr0[r] = __expf(lg0[r] - mB);
        pr1[r] = __expf(lg1[r] - mB);
        sm1 += pr0[r] + pr1[r];
      }
      sm1 += __shfl_xor(sm1, 16);
      sm1 += __shfl_xor(sm1, 32);
      if (lane < 16) red2[w * 16 + lane] = sm1;
      if (bval) {
#pragma unroll
        for (int r = 0; r < 4; ++r) {
          const int t0 = w * 32 + kg * 4 + r;
          *(float*)(SP + ((bq * 1024 + t0 * 4) ^ swb)) = pr0[r];
          *(float*)(SP + ((bq * 1024 + (t0 + 16) * 4) ^ swb)) = pr1[r];
        }
      }
      __syncthreads();
    }

    // ========== P2: ctx on VALU (encW stream) -> x = relu(ep + ctxW) ==========
    {
      const int b2 = w & 3, ch = w >> 2;
      const int c0 = ch * 256 + lane * 4;
      const int sb2 = (b2 & 7) << 4;
      float inv = red2[b2];
#pragma unroll
      for (int q = 1; q < 8; ++q) inv += red2[q * 16 + b2];
      inv = 1.f / inv;
      float acc0 = 0.f, acc1 = 0.f, acc2 = 0.f, acc3 = 0.f;
      const u16* ep2 = W16 + O16_ENC + (size_t)(bg0 + b2) * 512 + c0;
#pragma unroll 4
      for (int t = 0; t < 256; ++t) {
        const float prt = *(const float*)(SP + ((b2 * 1024 + t * 4) ^ sb2));
        const short4v v = *(const short4v*)(ep2 + (size_t)t * 65536);
        acc0 = fmaf(prt, bf2f((u16)v[0]), acc0);
        acc1 = fmaf(prt, bf2f((u16)v[1]), acc1);
        acc2 = fmaf(prt, bf2f((u16)v[2]), acc2);
        acc3 = fmaf(prt, bf2f((u16)v[3]), acc3);
      }
      __syncthreads();  // all pr reads done; safe to overlay x
      const short4v evv = *(const short4v*)(SX + ((b2 * 1024 + c0 * 2) ^ sb2));
      short4v xo;
      xo[0] = (short)f2bf(fmaxf(bf2f((u16)evv[0]) + acc0 * inv, 0.f));
      xo[1] = (short)f2bf(fmaxf(bf2f((u16)evv[1]) + acc1 * inv, 0.f));
      xo[2] = (short)f2bf(fmaxf(bf2f((u16)evv[2]) + acc2 * inv, 0.f));
      xo[3] = (short)f2bf(fmaxf(bf2f((u16)evv[3]) + acc3 * inv, 0.f));
      *(short4v*)(SP + ((b2 * 1024 + c0 * 2) ^ sb2)) = xo;
    }
    __syncthreads();

    // ========== P3: gi (accumulate into R,Z; INN new) + gates + h_new ==========
    {
      f32x4 INN[4];
#pragma unroll
      for (int j = 0; j < 4; ++j)
#pragma unroll
        for (int r = 0; r < 4; ++r) INN[j][r] = bih[1024 + (4 * w + j) * 16 + kg * 4 + r];
#pragma unroll 1
      for (int kt = 0; kt < 16; ++kt) {
        const short8 bb = ldB(SP, 1024, kt * 32, bq, kg);
#pragma unroll
        for (int j = 0; j < 4; ++j) {
          R[j] = MFMA16(ldA(WIH, 512, (4 * w + j) * 16 + bq, kt * 32, kg), bb, R[j]);
          Z[j] = MFMA16(ldA(WIH, 512, 512 + (4 * w + j) * 16 + bq, kt * 32, kg), bb, Z[j]);
          INN[j] = MFMA16(ldA(WIH, 512, 1024 + (4 * w + j) * 16 + bq, kt * 32, kg), bb, INN[j]);
        }
      }
      if (bval) {
#pragma unroll
        for (int j = 0; j < 4; ++j)
#pragma unroll
          for (int r = 0; r < 4; ++r) {
            const int c = (4 * w + j) * 16 + kg * 4 + r;
            const float rr = 1.f / (1.f + __expf(-R[j][r]));
            const float zz = 1.f / (1.f + __expf(-Z[j][r]));
            const float ex = __expf(2.f * (INN[j][r] + rr * HN[j][r]));
            const float nn = 1.f - 2.f / (ex + 1.f);
            const int hoff = (bq * 1024 + c * 2) ^ swb;
            const float ho = bf2f(*(const u16*)(SH + hoff));
            *(u16*)(SH + hoff) = f2bf((1.f - zz) * nn + zz * ho);
          }
      }
    }
    __syncthreads();

    // ========== P4: emissions + numerator + CRF + next-e staging ==========
    {
      f32x4 em0, em1;
#pragma unroll
      for (int r = 0; r < 4; ++r) {
        em0[r] = ob[w * 32 + kg * 4 + r];
        em1[r] = ob[w * 32 + 16 + kg * 4 + r];
      }
#pragma unroll 4
      for (int kt = 0; kt < 16; ++kt) {
        const short8 bb = ldB(SH, 1024, kt * 32, bq, kg);
        em0 = MFMA16(ldA(WOW, 512, w * 32 + bq, kt * 32, kg), bb, em0);
        em1 = MFMA16(ldA(WOW, 512, w * 32 + 16 + bq, kt * 32, kg), bb, em1);
      }
      if (bval) {
        const int tg = tags[s * 128 + bg0 + bq];
#pragma unroll
        for (int r = 0; r < 4; ++r) {
          if (w * 32 + kg * 4 + r == tg) nE2[bq] += em0[r];
          if (w * 32 + 16 + kg * 4 + r == tg) nE2[bq] += em1[r];
        }
      }
      if (s == 0) {
#pragma unroll
        for (int r = 0; r < 4; ++r) {
          sr0[r] = cs[w * 32 + kg * 4 + r] + em0[r];
          sr1[r] = cs[w * 32 + 16 + kg * 4 + r] + em1[r];
        }
      } else {
        float pm = sr0[0];
#pragma unroll
        for (int r = 1; r < 4; ++r) pm = fmaxf(pm, sr0[r]);
#pragma unroll
        for (int r = 0; r < 4; ++r) pm = fmaxf(pm, sr1[r]);
        pm = fmaxf(pm, __shfl_xor(pm, 16));
        pm = fmaxf(pm, __shfl_xor(pm, 32));
        if (lane < 16) red[w * 16 + lane] = pm;
        __syncthreads();
        float mf = red[bq];
#pragma unroll
        for (int q = 1; q < 8; ++q) mf = fmaxf(mf, red[q * 16 + bq]);
        if (bval) {
#pragma unroll
          for (int r = 0; r < 4; ++r) {
            const int k0 = w * 32 + kg * 4 + r;
            *(u16*)(SX + ((bq * 1024 + k0 * 2) ^ swb)) = f2bf(__expf(sr0[r] - mf));
            *(u16*)(SX + ((bq * 1024 + (k0 + 16) * 2) ^ swb)) = f2bf(__expf(sr1[r] - mf));
          }
        }
        if (w == 0 && lane < 16) O16[lane] += mf;
        __syncthreads();
        f32x4 d0 = {0.f, 0.f, 0.f, 0.f};
        f32x4 d1 = {0.f, 0.f, 0.f, 0.f};
#pragma unroll 4
        for (int kt = 0; kt < 8; ++kt) {
          const short8 bb = ldB(SX, 1024, kt * 32, bq, kg);
          d0 = MFMA16(ldA(WXT, 256, w * 32 + bq, kt * 32, kg), bb, d0);
          d1 = MFMA16(ldA(WXT, 256, w * 32 + 16 + bq, kt * 32, kg), bb, d1);
        }
#pragma unroll
        for (int r = 0; r < 4; ++r) {
          sr0[r] = __logf(d0[r]) + em0[r];
          sr1[r] = __logf(d1[r]) + em1[r];
        }
      }
      // stage e for step s+1 (teacher forcing: emb[output_tensor[s]])
      if (w < 4 && s < 255) {
        const int tok = tags[s * 128 + bg0 + w];
        const f32x4 ev = *(const f32x4*)(emb + (size_t)tok * 256 + lane * 4);
        short4v ee;
        ee[0] = (short)f2bf(ev[0]); ee[1] = (short)f2bf(ev[1]);
        ee[2] = (short)f2bf(ev[2]); ee[3] = (short)f2bf(ev[3]);
        *(short4v*)(SE + ((w * 512 + lane * 8) ^ ((w & 7) << 4))) = ee;
      }
    }
    __syncthreads();
  }

  // ========== final: denominator + llh per b ==========
  {
    float v0[4], v1[4];
    float pm = -3.0e38f;
#pragma unroll
    for (int r = 0; r < 4; ++r) {
      v0[r] = sr0[r] + ce[w * 32 + kg * 4 + r];
      v1[r] = sr1[r] + ce[w * 32 + 16 + kg * 4 + r];
      pm = fmaxf(pm, fmaxf(v0[r], v1[r]));
    }
    pm = fmaxf(pm, __shfl_xor(pm, 16));
    pm = fmaxf(pm, __shfl_xor(pm, 32));
    if (lane < 16) red[w * 16 + lane] = pm;
    __syncthreads();
    float mf = red[bq];
#pragma unroll
    for (int q = 1; q < 8; ++q) mf = fmaxf(mf, red[q * 16 + bq]);
    float ss = 0.f;
#pragma unroll
    for (int r = 0; r < 4; ++r) ss += __expf(v0[r] - mf) + __expf(v1[r] - mf);
    ss += __shfl_xor(ss, 16);
    ss += __shfl_xor(ss, 32);
    if (lane < 16) red2[w * 16 + lane] = ss;
    __syncthreads();
    if (w == 0 && lane < 4) {
      const int b = lane;
      float mfv = red[b];
      float sv = red2[b];
#pragma unroll
      for (int q = 1; q < 8; ++q) {
        mfv = fmaxf(mfv, red[q * 16 + b]);
        sv += red2[q * 16 + b];
      }
      const float den = O16[b] + mfv + __logf(sv);
      ws[OF_LLH + bg0 + b] = ws[OF_NS + bg0 + b] + nE2[b] - den;
    }
  }
}

// ---------------- final mean ----------------
__global__ void kFinal(const float* __restrict__ ws, float* __restrict__ out) {
  const int l = threadIdx.x;  // 64
  float v = ws[OF_LLH + l] + ws[OF_LLH + 64 + l];
#pragma unroll
  for (int o = 32; o; o >>= 1) v += __shfl_xor(v, o);
  if (l == 0) out[0] = v * (1.f / 128.f);
}

extern "C" void kernel_launch(void* const* d_in, const int* in_sizes, int n_in,
                              void* d_out, int out_size, void* d_ws, size_t ws_size,
                              hipStream_t stream) {
  (void)in_sizes; (void)n_in; (void)out_size; (void)ws_size;
  const int* dec = (const int*)d_in[0];
  const int* tags = (const int*)d_in[1];
  const float* enc = (const float*)d_in[2];
  const float* emb = (const float*)d_in[3];
  const float* aW = (const float*)d_in[4];
  const float* ab = (const float*)d_in[5];
  const float* cW = (const float*)d_in[6];
  const float* cb = (const float*)d_in[7];
  const float* wih = (const float*)d_in[8];
  const float* whh = (const float*)d_in[9];
  const float* bih = (const float*)d_in[10];
  const float* bhh = (const float*)d_in[11];
  const float* oW = (const float*)d_in[12];
  const float* ob = (const float*)d_in[13];
  const float* cs = (const float*)d_in[14];
  const float* ce = (const float*)d_in[15];
  const float* ct = (const float*)d_in[16];
  float* ws = (float*)d_ws;
  float* out = (float*)d_out;

  kPrep<<<dim3(8192), dim3(256), 0, stream>>>(wih, whh, aW, oW, cW, ct, ws);
  kNS<<<dim3(1), dim3(128), 0, stream>>>(tags, cs, ce, ct, ws);
  kEncW<<<dim3(2048), dim3(256), 0, stream>>>(enc, cW, (u16*)d_ws);
  maink<<<dim3(32), dim3(512), 0, stream>>>(dec, tags, emb, ab, cb, bih, bhh, ob, cs, ce, ws);
  kFinal<<<dim3(1), dim3(64), 0, stream>>>(ws, out);
}

// Round 4
// 34625.732 us; speedup vs baseline: 1.7811x; 1.5113x over previous
//
#include <hip/hip_runtime.h>
#include <hip/hip_cooperative_groups.h>

namespace cg = cooperative_groups;

// Round 4: feature-split cooperative MFMA pipeline.
// 256 blocks x 512 threads, 3 grid syncs per step.
// P1: gh, attn-logits, em(prev), ep, CRF-A (max+exp of prev scores)
// P2: softmax + coalesced encT stream -> x ; numerator gather
// P3: gi (K-split over 2 waves) + gates -> h ; CRF-B (p@expT) ; e-stage

typedef unsigned short u16;
typedef unsigned int u32;
typedef __attribute__((ext_vector_type(8))) short short8;
typedef __attribute__((ext_vector_type(4))) short short4v;
typedef __attribute__((ext_vector_type(4))) float f32x4;

#define MFMA16(a, b, c) __builtin_amdgcn_mfma_f32_16x16x32_bf16((a), (b), (c), 0, 0, 0)

// ---- ws layout ----
// u16 element offsets (base = ws)
#define U_ENC 0u           // encT bf16 [128 b][256 t][512 c]  (32MB)
#define U_WHH 16777216u    // [1536][512]
#define U_WIH 17563648u    // [1536][512]
#define U_WAW 18350080u    // [256][768]
#define U_WOW 18546688u    // [256][512]
#define U_WCE 18677760u    // [512][256]
#define U_WXT 18808832u    // [256][256]  expT[kn][k] = exp(trans[k][kn])
#define U_HB  18874368u    // h bf16 [128][512]
#define U_EB  18939904u    // e bf16 [128][256]
#define U_XB  18972672u    // x bf16 [128][512]
#define U_PB  19038208u    // p bf16 [128][256]
// f32 element offsets (base = ws)
#define F_LGB 9535488u     // logits f32 [128][256]
#define F_EMB 9568256u     // emissions f32 [128][256]
#define F_EPB 9601024u     // ep f32 [128][512]
#define F_GHB 9666560u     // gh f32 [128][1536]
#define F_SRB 9863168u     // CRF scores f32 [128][256]
#define F_MFB 9895936u     // [128]
#define F_NEB 9896064u     // [128]
#define F_NSB 9896192u     // [128]
// total ws use ~39.6MB (< 40MB known-present)

__device__ __forceinline__ float bf2f(u16 u) { return __uint_as_float(((u32)u) << 16); }
__device__ __forceinline__ u16 f2bf(float f) {
  u32 u = __float_as_uint(f);
  return (u16)((u + 0x7FFFu + ((u >> 16) & 1u)) >> 16);
}

// ---------------- weight convert to bf16 (2,097,152 elems) ----------------
__global__ void __launch_bounds__(256) kPrep(const float* __restrict__ wih,
                                             const float* __restrict__ whh,
                                             const float* __restrict__ aW,
                                             const float* __restrict__ oW,
                                             const float* __restrict__ cW,
                                             const float* __restrict__ ct,
                                             float* __restrict__ ws) {
  u16* W = (u16*)ws;
  const u32 i = blockIdx.x * 256 + threadIdx.x;
  if (i < 786432u) {
    W[U_WHH + i] = f2bf(whh[i]);
  } else if (i < 1572864u) {
    const u32 j = i - 786432u;
    W[U_WIH + j] = f2bf(wih[j]);
  } else if (i < 1769472u) {
    const u32 j = i - 1572864u;
    W[U_WAW + j] = f2bf(aW[j]);
  } else if (i < 1900544u) {
    const u32 j = i - 1769472u;
    W[U_WOW + j] = f2bf(oW[j]);
  } else if (i < 2031616u) {
    const u32 j = i - 1900544u;
    W[U_WCE + j] = f2bf(cW[(size_t)(j >> 8) * 1280 + (j & 255u)]);
  } else {
    const u32 j = i - 2031616u;
    const u32 kn = j >> 8, k = j & 255u;
    W[U_WXT + j] = f2bf(__expf(ct[k * 256u + kn]));
  }
}

// ---------------- init: zero h, stage e0, static numerator ----------------
__global__ void __launch_bounds__(256) kInit(const int* __restrict__ dec,
                                             const int* __restrict__ tags,
                                             const float* __restrict__ emb,
                                             const float* __restrict__ cs,
                                             const float* __restrict__ ce,
                                             const float* __restrict__ ct,
                                             float* __restrict__ ws) {
  const u32 idx = blockIdx.x * 256 + threadIdx.x;  // 65536
  u16* ENC = (u16*)ws;
  u16* HB = ENC + U_HB;
  u16* EB = ENC + U_EB;
  if (idx < 32768u) {
    ((u32*)HB)[idx] = 0u;  // zero h (128KB)
    const int b = idx >> 8, j = idx & 255;
    EB[idx] = f2bf(emb[(size_t)dec[b] * 256 + j]);
  }
  if (idx < 128u) {
    int prev = tags[idx];
    float a = cs[prev];
    for (int t = 1; t < 256; ++t) {
      const int cur = tags[t * 128 + idx];
      a += ct[prev * 256 + cur];
      prev = cur;
    }
    ws[F_NSB + idx] = a + ce[prev];
    ws[F_NEB + idx] = 0.f;
  }
}

// ---------------- encT[b][t][c] = sum_j enc[t,b,j] * comb_W[c, 256+j] (bf16) ----------------
__global__ void __launch_bounds__(256) kEncW(const float* __restrict__ enc,
                                             const float* __restrict__ cW,
                                             u16* __restrict__ encT) {
  __shared__ float wL[64 * 64];
  const int t = blockIdx.x >> 3, cblk = blockIdx.x & 7;
  const int tid = threadIdx.x;
  const int bg = tid & 31;   // b = bg*4 .. +3
  const int cg = tid >> 5;   // c = cblk*64 + cg*8 .. +7
  float acc[4][8];
#pragma unroll
  for (int i = 0; i < 4; ++i)
#pragma unroll
    for (int c = 0; c < 8; ++c) acc[i][c] = 0.f;
  const float* encB = enc + (size_t)t * (128 * 1024);
  for (int jt = 0; jt < 16; ++jt) {
    const int j0 = jt * 64;
    __syncthreads();
    for (int i = tid; i < 4096; i += 256) {
      const int cc = i >> 6, jj = i & 63;
      wL[cc * 64 + jj] = cW[(size_t)(cblk * 64 + cc) * 1280 + 256 + j0 + jj];
    }
    __syncthreads();
    for (int jj = 0; jj < 64; ++jj) {
      const float e0 = encB[(bg * 4 + 0) * 1024 + j0 + jj];
      const float e1 = encB[(bg * 4 + 1) * 1024 + j0 + jj];
      const float e2 = encB[(bg * 4 + 2) * 1024 + j0 + jj];
      const float e3 = encB[(bg * 4 + 3) * 1024 + j0 + jj];
#pragma unroll
      for (int c = 0; c < 8; ++c) {
        const float wv = wL[(cg * 8 + c) * 64 + jj];
        acc[0][c] = fmaf(e0, wv, acc[0][c]);
        acc[1][c] = fmaf(e1, wv, acc[1][c]);
        acc[2][c] = fmaf(e2, wv, acc[2][c]);
        acc[3][c] = fmaf(e3, wv, acc[3][c]);
      }
    }
  }
#pragma unroll
  for (int i = 0; i < 4; ++i)
    for (int c = 0; c < 8; ++c) {
      const int b = bg * 4 + i, cc = cblk * 64 + cg * 8 + c;
      encT[(size_t)b * 131072u + (size_t)t * 512u + cc] = f2bf(acc[i][c]);
    }
}

struct P9 {
  const int* dec; const int* tags; const float* emb;
  const float* ab; const float* cb; const float* bih; const float* bhh;
  const float* ob; const float* cs;
  float* ws;
};

// ---------------- main cooperative kernel ----------------
__global__ void __launch_bounds__(512) maink(P9 p) {
  cg::grid_group grid = cg::this_grid();
  float* const ws = p.ws;
  u16* const ENC = (u16*)ws;
  const u16* const WHH16 = ENC + U_WHH;
  const u16* const WIH16 = ENC + U_WIH;
  const u16* const WAW16 = ENC + U_WAW;
  const u16* const WOW16 = ENC + U_WOW;
  const u16* const WCE16 = ENC + U_WCE;
  const u16* const WXT16 = ENC + U_WXT;
  u16* const HB = ENC + U_HB;
  u16* const EB = ENC + U_EB;
  u16* const XB = ENC + U_XB;
  u16* const PBu = ENC + U_PB;
  float* const LGB = ws + F_LGB;
  float* const EMB = ws + F_EMB;
  float* const EPB = ws + F_EPB;
  float* const GHB = ws + F_GHB;
  float* const SRB = ws + F_SRB;
  float* const MFB = ws + F_MFB;
  float* const NEB = ws + F_NEB;

  __shared__ float prL[256];
  __shared__ float pacc[2][512];
  __shared__ float red[16];
  __shared__ float pr3[3][256];

  const int tid = threadIdx.x;
  const int w = tid >> 6, lane = tid & 63;
  const int bq = lane & 15, kg = lane >> 4;
  const int blk = blockIdx.x;

  for (int s = 0; s <= 256; ++s) {
    // ================= P1 =================
    if (w < 3) {
      if (s < 256) {  // gh task: t = w*256+blk in [0,768)
        const int t = w * 256 + blk;
        const int r0 = (t >> 3) * 16, b0 = (t & 7) * 16;
        f32x4 acc;
        const float4 bs = *(const float4*)(p.bhh + r0 + kg * 4);
        acc[0] = bs.x; acc[1] = bs.y; acc[2] = bs.z; acc[3] = bs.w;
        const u16* Ar = WHH16 + (size_t)(r0 + bq) * 512 + kg * 8;
        const u16* Br = HB + (size_t)(b0 + bq) * 512 + kg * 8;
#pragma unroll 4
        for (int kt = 0; kt < 16; ++kt)
          acc = MFMA16(*(const short8*)(Ar + kt * 32), *(const short8*)(Br + kt * 32), acc);
        float4 o; o.x = acc[0]; o.y = acc[1]; o.z = acc[2]; o.w = acc[3];
        *reinterpret_cast<float4*>(GHB + (size_t)(b0 + bq) * 1536 + r0 + kg * 4) = o;
      }
    } else if (w == 3) {
      if (blk < 128) {
        if (s < 256) {  // attn logits, K=768
          const int r0 = (blk >> 3) * 16, b0 = (blk & 7) * 16;
          f32x4 acc;
          const float4 bs = *(const float4*)(p.ab + r0 + kg * 4);
          acc[0] = bs.x; acc[1] = bs.y; acc[2] = bs.z; acc[3] = bs.w;
          const u16* Ar = WAW16 + (size_t)(r0 + bq) * 768 + kg * 8;
          const u16* Be = EB + (size_t)(b0 + bq) * 256 + kg * 8;
          const u16* Bh = HB + (size_t)(b0 + bq) * 512 + kg * 8;
#pragma unroll 4
          for (int kt = 0; kt < 8; ++kt)
            acc = MFMA16(*(const short8*)(Ar + kt * 32), *(const short8*)(Be + kt * 32), acc);
#pragma unroll 4
          for (int kt = 0; kt < 16; ++kt)
            acc = MFMA16(*(const short8*)(Ar + 256 + kt * 32), *(const short8*)(Bh + kt * 32), acc);
          float4 o; o.x = acc[0]; o.y = acc[1]; o.z = acc[2]; o.w = acc[3];
          *reinterpret_cast<float4*>(LGB + (size_t)(b0 + bq) * 256 + r0 + kg * 4) = o;
        }
      } else {
        if (s >= 1) {  // em_{s-1} from current h
          const int t2 = blk - 128;
          const int r0 = (t2 >> 3) * 16, b0 = (t2 & 7) * 16;
          f32x4 acc;
          const float4 bs = *(const float4*)(p.ob + r0 + kg * 4);
          acc[0] = bs.x; acc[1] = bs.y; acc[2] = bs.z; acc[3] = bs.w;
          const u16* Ar = WOW16 + (size_t)(r0 + bq) * 512 + kg * 8;
          const u16* Br = HB + (size_t)(b0 + bq) * 512 + kg * 8;
#pragma unroll 4
          for (int kt = 0; kt < 16; ++kt)
            acc = MFMA16(*(const short8*)(Ar + kt * 32), *(const short8*)(Br + kt * 32), acc);
          float4 o; o.x = acc[0]; o.y = acc[1]; o.z = acc[2]; o.w = acc[3];
          *reinterpret_cast<float4*>(EMB + (size_t)(b0 + bq) * 256 + r0 + kg * 4) = o;
        }
      }
    } else if (w == 4) {
      if (s < 256) {  // ep = cb + cWe @ e, K=256
        const int r0 = (blk >> 3) * 16, b0 = (blk & 7) * 16;
        f32x4 acc;
        const float4 bs = *(const float4*)(p.cb + r0 + kg * 4);
        acc[0] = bs.x; acc[1] = bs.y; acc[2] = bs.z; acc[3] = bs.w;
        const u16* Ar = WCE16 + (size_t)(r0 + bq) * 256 + kg * 8;
        const u16* Br = EB + (size_t)(b0 + bq) * 256 + kg * 8;
#pragma unroll 4
        for (int kt = 0; kt < 8; ++kt)
          acc = MFMA16(*(const short8*)(Ar + kt * 32), *(const short8*)(Br + kt * 32), acc);
        float4 o; o.x = acc[0]; o.y = acc[1]; o.z = acc[2]; o.w = acc[3];
        *reinterpret_cast<float4*>(EPB + (size_t)(b0 + bq) * 512 + r0 + kg * 4) = o;
      }
    } else if (w == 5) {
      if (blk < 128 && s >= 2) {  // CRF-A: mf + p = exp(sr - mf)
        const int b = blk;
        const float4 sv = *(const float4*)(SRB + (size_t)b * 256 + lane * 4);
        float mx = fmaxf(fmaxf(sv.x, sv.y), fmaxf(sv.z, sv.w));
#pragma unroll
        for (int o = 32; o; o >>= 1) mx = fmaxf(mx, __shfl_xor(mx, o));
        short4v pv;
        pv[0] = (short)f2bf(__expf(sv.x - mx));
        pv[1] = (short)f2bf(__expf(sv.y - mx));
        pv[2] = (short)f2bf(__expf(sv.z - mx));
        pv[3] = (short)f2bf(__expf(sv.w - mx));
        *reinterpret_cast<short4v*>(PBu + (size_t)b * 256 + lane * 4) = pv;
        if (lane == 0) MFB[b] = mx;
      }
    }
    grid.sync();

    // ================= P2 =================
    if (blk < 128) {
      const int b = blk;
      if (s < 256) {
        float v = (tid < 256) ? LGB[(size_t)b * 256 + tid] : -3.0e38f;
        float m = v;
#pragma unroll
        for (int o = 32; o; o >>= 1) m = fmaxf(m, __shfl_xor(m, o));
        if (lane == 0) red[w] = m;
        __syncthreads();
        float mB = red[0];
#pragma unroll
        for (int q = 1; q < 8; ++q) mB = fmaxf(mB, red[q]);
        float e = 0.f;
        if (tid < 256) { e = __expf(v - mB); prL[tid] = e; }
        float sacc = e;
#pragma unroll
        for (int o = 32; o; o >>= 1) sacc += __shfl_xor(sacc, o);
        if (lane == 0) red[8 + w] = sacc;
        __syncthreads();
        float sum = red[8];
#pragma unroll
        for (int q = 1; q < 8; ++q) sum += red[8 + q];
        const float inv = 1.f / sum;
        // coalesced encT stream: thread = (half of t, c-pair)
        const int half = tid >> 8, cp = tid & 255;
        const int c0 = cp * 2;
        const u16* base = ENC + (size_t)b * 131072u + (size_t)(half * 128) * 512u + c0;
        const float* prh = prL + half * 128;
        float a0 = 0.f, a1 = 0.f;
#pragma unroll 8
        for (int t = 0; t < 128; ++t) {
          const float prt = prh[t];
          const u32 vv = *(const u32*)(base + (size_t)t * 512);
          a0 = fmaf(prt, bf2f((u16)(vv & 0xffffu)), a0);
          a1 = fmaf(prt, bf2f((u16)(vv >> 16)), a1);
        }
        pacc[half][c0] = a0;
        pacc[half][c0 + 1] = a1;
        __syncthreads();
        {
          const int c = tid;
          const float xv = fmaxf(EPB[(size_t)b * 512 + c] + (pacc[0][c] + pacc[1][c]) * inv, 0.f);
          XB[(size_t)b * 512 + c] = f2bf(xv);
        }
      }
      if (s >= 1 && tid == 0)
        NEB[b] += EMB[(size_t)b * 256 + p.tags[(s - 1) * 128 + b]];
    }
    grid.sync();

    // ================= P3 =================
    f32x4 R, Z, N;
    const bool giact = (s < 256) && (w == 0 || w == 2);
    if (giact) {
      const int r0 = (blk >> 3) * 16, b0 = (blk & 7) * 16;
      const int kh = w >> 1;  // K half
      if (kh == 0) {
        const float4 b1 = *(const float4*)(p.bih + r0 + kg * 4);
        const float4 b2 = *(const float4*)(p.bih + 512 + r0 + kg * 4);
        const float4 b3 = *(const float4*)(p.bih + 1024 + r0 + kg * 4);
        R[0] = b1.x; R[1] = b1.y; R[2] = b1.z; R[3] = b1.w;
        Z[0] = b2.x; Z[1] = b2.y; Z[2] = b2.z; Z[3] = b2.w;
        N[0] = b3.x; N[1] = b3.y; N[2] = b3.z; N[3] = b3.w;
      } else {
        R = (f32x4){0.f, 0.f, 0.f, 0.f}; Z = R; N = R;
      }
      const u16* ArR = WIH16 + (size_t)(r0 + bq) * 512 + kh * 256 + kg * 8;
      const u16* ArZ = ArR + (size_t)512 * 512;
      const u16* ArN = ArR + (size_t)1024 * 512;
      const u16* Br = XB + (size_t)(b0 + bq) * 512 + kh * 256 + kg * 8;
#pragma unroll 2
      for (int kt = 0; kt < 8; ++kt) {
        const short8 bb = *(const short8*)(Br + kt * 32);
        R = MFMA16(*(const short8*)(ArR + kt * 32), bb, R);
        Z = MFMA16(*(const short8*)(ArZ + kt * 32), bb, Z);
        N = MFMA16(*(const short8*)(ArN + kt * 32), bb, N);
      }
      if (w == 2) {
#pragma unroll
        for (int r = 0; r < 4; ++r) {
          pr3[0][(kg * 4 + r) * 16 + bq] = R[r];
          pr3[1][(kg * 4 + r) * 16 + bq] = Z[r];
          pr3[2][(kg * 4 + r) * 16 + bq] = N[r];
        }
      }
    }
    __syncthreads();
    if (s < 256 && w == 0) {  // combine + gates + h_new
      const int r0 = (blk >> 3) * 16, b0 = (blk & 7) * 16;
      const int b = b0 + bq;
      const float4 gr4 = *(const float4*)(GHB + (size_t)b * 1536 + r0 + kg * 4);
      const float4 gz4 = *(const float4*)(GHB + (size_t)b * 1536 + 512 + r0 + kg * 4);
      const float4 gn4 = *(const float4*)(GHB + (size_t)b * 1536 + 1024 + r0 + kg * 4);
      const float grA[4] = {gr4.x, gr4.y, gr4.z, gr4.w};
      const float gzA[4] = {gz4.x, gz4.y, gz4.z, gz4.w};
      const float gnA[4] = {gn4.x, gn4.y, gn4.z, gn4.w};
      short4v h4 = *reinterpret_cast<short4v*>(HB + (size_t)b * 512 + r0 + kg * 4);
      short4v ho;
#pragma unroll
      for (int r = 0; r < 4; ++r) {
        const float Rv = R[r] + pr3[0][(kg * 4 + r) * 16 + bq];
        const float Zv = Z[r] + pr3[1][(kg * 4 + r) * 16 + bq];
        const float Nv = N[r] + pr3[2][(kg * 4 + r) * 16 + bq];
        const float rr = 1.f / (1.f + __expf(-(Rv + grA[r])));
        const float zz = 1.f / (1.f + __expf(-(Zv + gzA[r])));
        const float nn = tanhf(Nv + rr * gnA[r]);
        const float hold = bf2f((u16)h4[r]);
        ho[r] = (short)f2bf((1.f - zz) * nn + zz * hold);
      }
      *reinterpret_cast<short4v*>(HB + (size_t)b * 512 + r0 + kg * 4) = ho;
    }
    if (w == 1) {
      if (blk < 128) {
        if (s >= 1) {  // CRF-B
          const int kn0 = (blk >> 3) * 16, b0 = (blk & 7) * 16;
          const int b = b0 + bq;
          if (s == 1) {
            const float4 e4 = *(const float4*)(EMB + (size_t)b * 256 + kn0 + kg * 4);
            const float4 c4 = *(const float4*)(p.cs + kn0 + kg * 4);
            float4 o; o.x = c4.x + e4.x; o.y = c4.y + e4.y; o.z = c4.z + e4.z; o.w = c4.w + e4.w;
            *reinterpret_cast<float4*>(SRB + (size_t)b * 256 + kn0 + kg * 4) = o;
          } else {
            f32x4 acc = (f32x4){0.f, 0.f, 0.f, 0.f};
            const u16* Ar = WXT16 + (size_t)(kn0 + bq) * 256 + kg * 8;
            const u16* Br = PBu + (size_t)(b0 + bq) * 256 + kg * 8;
#pragma unroll 4
            for (int kt = 0; kt < 8; ++kt)
              acc = MFMA16(*(const short8*)(Ar + kt * 32), *(const short8*)(Br + kt * 32), acc);
            const float mf = MFB[b];
            const float4 e4 = *(const float4*)(EMB + (size_t)b * 256 + kn0 + kg * 4);
            float4 o;
            o.x = mf + __logf(acc[0]) + e4.x;
            o.y = mf + __logf(acc[1]) + e4.y;
            o.z = mf + __logf(acc[2]) + e4.z;
            o.w = mf + __logf(acc[3]) + e4.w;
            *reinterpret_cast<float4*>(SRB + (size_t)b * 256 + kn0 + kg * 4) = o;
          }
        }
      } else {
        if (s < 255) {  // stage e_{s+1}
          const int b = blk - 128;
          const int tok = p.tags[s * 128 + b];
          const float4 ev = *(const float4*)(p.emb + (size_t)tok * 256 + lane * 4);
          short4v ee;
          ee[0] = (short)f2bf(ev.x); ee[1] = (short)f2bf(ev.y);
          ee[2] = (short)f2bf(ev.z); ee[3] = (short)f2bf(ev.w);
          *reinterpret_cast<short4v*>(EB + (size_t)b * 256 + lane * 4) = ee;
        }
      }
    }
    grid.sync();
  }
}

// ---------------- final: denominator + mean ----------------
__global__ void __launch_bounds__(128) kFinal(const float* __restrict__ ws,
                                              const float* __restrict__ ce,
                                              float* __restrict__ out) {
  __shared__ float acc[128];
  const int tid = threadIdx.x;  // 128
  const float* SRB = ws + F_SRB;
  float mx = -3.0e38f;
#pragma unroll 8
  for (int k = 0; k < 256; ++k) mx = fmaxf(mx, SRB[(size_t)tid * 256 + k] + ce[k]);
  float sm = 0.f;
#pragma unroll 8
  for (int k = 0; k < 256; ++k) sm += __expf(SRB[(size_t)tid * 256 + k] + ce[k] - mx);
  acc[tid] = ws[F_NSB + tid] + ws[F_NEB + tid] - (mx + __logf(sm));
  __syncthreads();
  if (tid < 64) {
    float v = acc[tid] + acc[tid + 64];
#pragma unroll
    for (int o = 32; o; o >>= 1) v += __shfl_xor(v, o);
    if (tid == 0) out[0] = v * (1.f / 128.f);
  }
}

extern "C" void kernel_launch(void* const* d_in, const int* in_sizes, int n_in,
                              void* d_out, int out_size, void* d_ws, size_t ws_size,
                              hipStream_t stream) {
  (void)in_sizes; (void)n_in; (void)out_size; (void)ws_size;
  const int* dec = (const int*)d_in[0];
  const int* tags = (const int*)d_in[1];
  const float* enc = (const float*)d_in[2];
  const float* emb = (const float*)d_in[3];
  const float* aW = (const float*)d_in[4];
  const float* ab = (const float*)d_in[5];
  const float* cW = (const float*)d_in[6];
  const float* cb = (const float*)d_in[7];
  const float* wih = (const float*)d_in[8];
  const float* whh = (const float*)d_in[9];
  const float* bih = (const float*)d_in[10];
  const float* bhh = (const float*)d_in[11];
  const float* oW = (const float*)d_in[12];
  const float* ob = (const float*)d_in[13];
  const float* cs = (const float*)d_in[14];
  const float* ce = (const float*)d_in[15];
  const float* ct = (const float*)d_in[16];
  float* ws = (float*)d_ws;
  float* out = (float*)d_out;

  kPrep<<<dim3(8192), dim3(256), 0, stream>>>(wih, whh, aW, oW, cW, ct, ws);
  kInit<<<dim3(256), dim3(256), 0, stream>>>(dec, tags, emb, cs, ce, ct, ws);
  kEncW<<<dim3(2048), dim3(256), 0, stream>>>(enc, cW, (u16*)d_ws);

  P9 p;
  p.dec = dec; p.tags = tags; p.emb = emb;
  p.ab = ab; p.cb = cb; p.bih = bih; p.bhh = bhh;
  p.ob = ob; p.cs = cs; p.ws = ws;
  void* args[] = { &p };
  hipLaunchCooperativeKernel((void*)maink, dim3(256), dim3(512), args, 0, stream);

  kFinal<<<dim3(1), dim3(128), 0, stream>>>(ws, ce, out);
}

// Round 5
// 24272.618 us; speedup vs baseline: 2.5408x; 1.4265x over previous
//
#include <hip/hip_runtime.h>

// Round 5: R4 structure + custom fast grid barrier (replaces cg::grid.sync),
// P2 encT stream split across block pairs, deeper unrolls.
// 256 blocks x 512 threads, 3 barriers per step.

typedef unsigned short u16;
typedef unsigned int u32;
typedef __attribute__((ext_vector_type(8))) short short8;
typedef __attribute__((ext_vector_type(4))) short short4v;
typedef __attribute__((ext_vector_type(4))) float f32x4;

#define MFMA16(a, b, c) __builtin_amdgcn_mfma_f32_16x16x32_bf16((a), (b), (c), 0, 0, 0)

// ---- ws layout ----
// u16 element offsets (base = ws)
#define U_ENC 0u           // encT bf16 [128 b][256 t][512 c]  (32MB)
#define U_WHH 16777216u    // [1536][512]
#define U_WIH 17563648u    // [1536][512]
#define U_WAW 18350080u    // [256][768]
#define U_WOW 18546688u    // [256][512]
#define U_WCE 18677760u    // [512][256]
#define U_WXT 18808832u    // [256][256]  expT[kn][k] = exp(trans[k][kn])
#define U_HB  18874368u    // h bf16 [128][512]
#define U_EB  18939904u    // e bf16 [128][256]
#define U_XB  18972672u    // x bf16 [128][512]
#define U_PB  19038208u    // p bf16 [128][256]
// f32 element offsets (base = ws)
#define F_LGB 9535488u     // logits f32 [128][256]
#define F_EMB 9568256u     // emissions f32 [128][256]
#define F_EPB 9601024u     // ep f32 [128][512]
#define F_GHB 9666560u     // gh f32 [128][1536]
#define F_SRB 9863168u     // CRF scores f32 [128][256]
#define F_MFB 9895936u     // [128]
#define F_NEB 9896064u     // [128]
#define F_NSB 9896192u     // [128]
#define F_BARC 9896320u    // barrier counter (u32)

__device__ __forceinline__ float bf2f(u16 u) { return __uint_as_float(((u32)u) << 16); }
__device__ __forceinline__ u16 f2bf(float f) {
  u32 u = __float_as_uint(f);
  return (u16)((u + 0x7FFFu + ((u >> 16) & 1u)) >> 16);
}

// fast grid barrier: generation target = gen*256, counter zeroed per launch by kInit
__device__ __forceinline__ void gbar(u32* cnt, u32 target) {
  __syncthreads();
  if (threadIdx.x == 0) {
    __threadfence();          // release: my writes visible device-wide
    atomicAdd(cnt, 1u);       // device-scope arrive
    while (__hip_atomic_load(cnt, __ATOMIC_RELAXED, __HIP_MEMORY_SCOPE_AGENT) < target) {}
    __threadfence();          // acquire: see others' writes
  }
  __syncthreads();
}

// ---------------- weight convert to bf16 (2,097,152 elems) ----------------
__global__ void __launch_bounds__(256) kPrep(const float* __restrict__ wih,
                                             const float* __restrict__ whh,
                                             const float* __restrict__ aW,
                                             const float* __restrict__ oW,
                                             const float* __restrict__ cW,
                                             const float* __restrict__ ct,
                                             float* __restrict__ ws) {
  u16* W = (u16*)ws;
  const u32 i = blockIdx.x * 256 + threadIdx.x;
  if (i < 786432u) {
    W[U_WHH + i] = f2bf(whh[i]);
  } else if (i < 1572864u) {
    const u32 j = i - 786432u;
    W[U_WIH + j] = f2bf(wih[j]);
  } else if (i < 1769472u) {
    const u32 j = i - 1572864u;
    W[U_WAW + j] = f2bf(aW[j]);
  } else if (i < 1900544u) {
    const u32 j = i - 1769472u;
    W[U_WOW + j] = f2bf(oW[j]);
  } else if (i < 2031616u) {
    const u32 j = i - 1900544u;
    W[U_WCE + j] = f2bf(cW[(size_t)(j >> 8) * 1280 + (j & 255u)]);
  } else {
    const u32 j = i - 2031616u;
    const u32 kn = j >> 8, k = j & 255u;
    W[U_WXT + j] = f2bf(__expf(ct[k * 256u + kn]));
  }
}

// ---------------- init: zero h, stage e0, static numerator, barrier counter ----------------
__global__ void __launch_bounds__(256) kInit(const int* __restrict__ dec,
                                             const int* __restrict__ tags,
                                             const float* __restrict__ emb,
                                             const float* __restrict__ cs,
                                             const float* __restrict__ ce,
                                             const float* __restrict__ ct,
                                             float* __restrict__ ws) {
  const u32 idx = blockIdx.x * 256 + threadIdx.x;  // 65536
  u16* ENC = (u16*)ws;
  u16* HB = ENC + U_HB;
  u16* EB = ENC + U_EB;
  if (idx < 32768u) {
    ((u32*)HB)[idx] = 0u;  // zero h (128KB)
    const int b = idx >> 8, j = idx & 255;
    EB[idx] = f2bf(emb[(size_t)dec[b] * 256 + j]);
  }
  if (idx < 128u) {
    int prev = tags[idx];
    float a = cs[prev];
    for (int t = 1; t < 256; ++t) {
      const int cur = tags[t * 128 + idx];
      a += ct[prev * 256 + cur];
      prev = cur;
    }
    ws[F_NSB + idx] = a + ce[prev];
    ws[F_NEB + idx] = 0.f;
  }
  if (idx == 0) *((u32*)(ws + F_BARC)) = 0u;
}

// ---------------- encT[b][t][c] = sum_j enc[t,b,j] * comb_W[c, 256+j] (bf16) ----------------
__global__ void __launch_bounds__(256) kEncW(const float* __restrict__ enc,
                                             const float* __restrict__ cW,
                                             u16* __restrict__ encT) {
  __shared__ float wL[64 * 64];
  const int t = blockIdx.x >> 3, cblk = blockIdx.x & 7;
  const int tid = threadIdx.x;
  const int bg = tid & 31;   // b = bg*4 .. +3
  const int cg = tid >> 5;   // c = cblk*64 + cg*8 .. +7
  float acc[4][8];
#pragma unroll
  for (int i = 0; i < 4; ++i)
#pragma unroll
    for (int c = 0; c < 8; ++c) acc[i][c] = 0.f;
  const float* encB = enc + (size_t)t * (128 * 1024);
  for (int jt = 0; jt < 16; ++jt) {
    const int j0 = jt * 64;
    __syncthreads();
    for (int i = tid; i < 4096; i += 256) {
      const int cc = i >> 6, jj = i & 63;
      wL[cc * 64 + jj] = cW[(size_t)(cblk * 64 + cc) * 1280 + 256 + j0 + jj];
    }
    __syncthreads();
    for (int jj = 0; jj < 64; ++jj) {
      const float e0 = encB[(bg * 4 + 0) * 1024 + j0 + jj];
      const float e1 = encB[(bg * 4 + 1) * 1024 + j0 + jj];
      const float e2 = encB[(bg * 4 + 2) * 1024 + j0 + jj];
      const float e3 = encB[(bg * 4 + 3) * 1024 + j0 + jj];
#pragma unroll
      for (int c = 0; c < 8; ++c) {
        const float wv = wL[(cg * 8 + c) * 64 + jj];
        acc[0][c] = fmaf(e0, wv, acc[0][c]);
        acc[1][c] = fmaf(e1, wv, acc[1][c]);
        acc[2][c] = fmaf(e2, wv, acc[2][c]);
        acc[3][c] = fmaf(e3, wv, acc[3][c]);
      }
    }
  }
#pragma unroll
  for (int i = 0; i < 4; ++i)
    for (int c = 0; c < 8; ++c) {
      const int b = bg * 4 + i, cc = cblk * 64 + cg * 8 + c;
      encT[(size_t)b * 131072u + (size_t)t * 512u + cc] = f2bf(acc[i][c]);
    }
}

struct P9 {
  const int* dec; const int* tags; const float* emb;
  const float* ab; const float* cb; const float* bih; const float* bhh;
  const float* ob; const float* cs;
  float* ws;
};

// ---------------- main cooperative kernel ----------------
__global__ void __launch_bounds__(512) maink(P9 p) {
  float* const ws = p.ws;
  u16* const ENC = (u16*)ws;
  const u16* const WHH16 = ENC + U_WHH;
  const u16* const WIH16 = ENC + U_WIH;
  const u16* const WAW16 = ENC + U_WAW;
  const u16* const WOW16 = ENC + U_WOW;
  const u16* const WCE16 = ENC + U_WCE;
  const u16* const WXT16 = ENC + U_WXT;
  u16* const HB = ENC + U_HB;
  u16* const EB = ENC + U_EB;
  u16* const XB = ENC + U_XB;
  u16* const PBu = ENC + U_PB;
  float* const LGB = ws + F_LGB;
  float* const EMB = ws + F_EMB;
  float* const EPB = ws + F_EPB;
  float* const GHB = ws + F_GHB;
  float* const SRB = ws + F_SRB;
  float* const MFB = ws + F_MFB;
  float* const NEB = ws + F_NEB;
  u32* const barc = (u32*)(ws + F_BARC);

  __shared__ float prL[256];
  __shared__ float pacc[4][256];
  __shared__ float red[16];
  __shared__ float pr3[3][256];

  const int tid = threadIdx.x;
  const int w = tid >> 6, lane = tid & 63;
  const int bq = lane & 15, kg = lane >> 4;
  const int blk = blockIdx.x;
  u32 gen = 0;

  for (int s = 0; s <= 256; ++s) {
    // ================= P1 =================
    if (w < 3) {
      if (s < 256) {  // gh task: t = w*256+blk in [0,768)
        const int t = w * 256 + blk;
        const int r0 = (t >> 3) * 16, b0 = (t & 7) * 16;
        f32x4 acc;
        const float4 bs = *(const float4*)(p.bhh + r0 + kg * 4);
        acc[0] = bs.x; acc[1] = bs.y; acc[2] = bs.z; acc[3] = bs.w;
        const u16* Ar = WHH16 + (size_t)(r0 + bq) * 512 + kg * 8;
        const u16* Br = HB + (size_t)(b0 + bq) * 512 + kg * 8;
#pragma unroll 8
        for (int kt = 0; kt < 16; ++kt)
          acc = MFMA16(*(const short8*)(Ar + kt * 32), *(const short8*)(Br + kt * 32), acc);
        float4 o; o.x = acc[0]; o.y = acc[1]; o.z = acc[2]; o.w = acc[3];
        *reinterpret_cast<float4*>(GHB + (size_t)(b0 + bq) * 1536 + r0 + kg * 4) = o;
      }
    } else if (w == 3) {
      if (blk < 128) {
        if (s < 256) {  // attn logits, K=768
          const int r0 = (blk >> 3) * 16, b0 = (blk & 7) * 16;
          f32x4 acc;
          const float4 bs = *(const float4*)(p.ab + r0 + kg * 4);
          acc[0] = bs.x; acc[1] = bs.y; acc[2] = bs.z; acc[3] = bs.w;
          const u16* Ar = WAW16 + (size_t)(r0 + bq) * 768 + kg * 8;
          const u16* Be = EB + (size_t)(b0 + bq) * 256 + kg * 8;
          const u16* Bh = HB + (size_t)(b0 + bq) * 512 + kg * 8;
#pragma unroll 4
          for (int kt = 0; kt < 8; ++kt)
            acc = MFMA16(*(const short8*)(Ar + kt * 32), *(const short8*)(Be + kt * 32), acc);
#pragma unroll 8
          for (int kt = 0; kt < 16; ++kt)
            acc = MFMA16(*(const short8*)(Ar + 256 + kt * 32), *(const short8*)(Bh + kt * 32), acc);
          float4 o; o.x = acc[0]; o.y = acc[1]; o.z = acc[2]; o.w = acc[3];
          *reinterpret_cast<float4*>(LGB + (size_t)(b0 + bq) * 256 + r0 + kg * 4) = o;
        }
      } else {
        if (s >= 1) {  // em_{s-1} from current h
          const int t2 = blk - 128;
          const int r0 = (t2 >> 3) * 16, b0 = (t2 & 7) * 16;
          f32x4 acc;
          const float4 bs = *(const float4*)(p.ob + r0 + kg * 4);
          acc[0] = bs.x; acc[1] = bs.y; acc[2] = bs.z; acc[3] = bs.w;
          const u16* Ar = WOW16 + (size_t)(r0 + bq) * 512 + kg * 8;
          const u16* Br = HB + (size_t)(b0 + bq) * 512 + kg * 8;
#pragma unroll 8
          for (int kt = 0; kt < 16; ++kt)
            acc = MFMA16(*(const short8*)(Ar + kt * 32), *(const short8*)(Br + kt * 32), acc);
          float4 o; o.x = acc[0]; o.y = acc[1]; o.z = acc[2]; o.w = acc[3];
          *reinterpret_cast<float4*>(EMB + (size_t)(b0 + bq) * 256 + r0 + kg * 4) = o;
        }
      }
    } else if (w == 4) {
      if (s < 256) {  // ep = cb + cWe @ e, K=256
        const int r0 = (blk >> 3) * 16, b0 = (blk & 7) * 16;
        f32x4 acc;
        const float4 bs = *(const float4*)(p.cb + r0 + kg * 4);
        acc[0] = bs.x; acc[1] = bs.y; acc[2] = bs.z; acc[3] = bs.w;
        const u16* Ar = WCE16 + (size_t)(r0 + bq) * 256 + kg * 8;
        const u16* Br = EB + (size_t)(b0 + bq) * 256 + kg * 8;
#pragma unroll 4
        for (int kt = 0; kt < 8; ++kt)
          acc = MFMA16(*(const short8*)(Ar + kt * 32), *(const short8*)(Br + kt * 32), acc);
        float4 o; o.x = acc[0]; o.y = acc[1]; o.z = acc[2]; o.w = acc[3];
        *reinterpret_cast<float4*>(EPB + (size_t)(b0 + bq) * 512 + r0 + kg * 4) = o;
      }
    } else if (w == 5) {
      if (blk < 128 && s >= 2) {  // CRF-A: mf + p = exp(sr - mf)
        const int b = blk;
        const float4 sv = *(const float4*)(SRB + (size_t)b * 256 + lane * 4);
        float mx = fmaxf(fmaxf(sv.x, sv.y), fmaxf(sv.z, sv.w));
#pragma unroll
        for (int o = 32; o; o >>= 1) mx = fmaxf(mx, __shfl_xor(mx, o));
        short4v pv;
        pv[0] = (short)f2bf(__expf(sv.x - mx));
        pv[1] = (short)f2bf(__expf(sv.y - mx));
        pv[2] = (short)f2bf(__expf(sv.z - mx));
        pv[3] = (short)f2bf(__expf(sv.w - mx));
        *reinterpret_cast<short4v*>(PBu + (size_t)b * 256 + lane * 4) = pv;
        if (lane == 0) MFB[b] = mx;
      }
    }
    gbar(barc, (++gen) * 256u);

    // ================= P2 (all 256 blocks; pair-split over c halves) =================
    {
      const int b = blk & 127, chalf = blk >> 7;
      if (s < 256) {
        float v = (tid < 256) ? LGB[(size_t)b * 256 + tid] : -3.0e38f;
        float m = v;
#pragma unroll
        for (int o = 32; o; o >>= 1) m = fmaxf(m, __shfl_xor(m, o));
        if (lane == 0) red[w] = m;
        __syncthreads();
        float mB = red[0];
#pragma unroll
        for (int q = 1; q < 8; ++q) mB = fmaxf(mB, red[q]);
        float e = 0.f;
        if (tid < 256) { e = __expf(v - mB); prL[tid] = e; }
        float sacc = e;
#pragma unroll
        for (int o = 32; o; o >>= 1) sacc += __shfl_xor(sacc, o);
        if (lane == 0) red[8 + w] = sacc;
        __syncthreads();
        float sum = red[8];
#pragma unroll
        for (int q = 1; q < 8; ++q) sum += red[8 + q];
        const float inv = 1.f / sum;
        // stream this block's c-half: 4 t-quarters x 128 c-pairs
        const int tq = tid >> 7, cp = tid & 127;
        const int c0l = cp * 2;
        const u16* base = ENC + (size_t)b * 131072u + (size_t)(tq * 64) * 512u + (chalf * 256 + c0l);
        const float* prh = prL + tq * 64;
        float a0 = 0.f, a1 = 0.f;
#pragma unroll 8
        for (int t = 0; t < 64; ++t) {
          const float prt = prh[t];
          const u32 vv = *(const u32*)(base + (size_t)t * 512);
          a0 = fmaf(prt, bf2f((u16)(vv & 0xffffu)), a0);
          a1 = fmaf(prt, bf2f((u16)(vv >> 16)), a1);
        }
        pacc[tq][c0l] = a0;
        pacc[tq][c0l + 1] = a1;
        __syncthreads();
        if (tid < 256) {
          const int cl = tid;
          const float xv = fmaxf(EPB[(size_t)b * 512 + chalf * 256 + cl] +
                                     (pacc[0][cl] + pacc[1][cl] + pacc[2][cl] + pacc[3][cl]) * inv,
                                 0.f);
          XB[(size_t)b * 512 + chalf * 256 + cl] = f2bf(xv);
        }
      }
      if (chalf == 0 && s >= 1 && tid == 0)
        NEB[b] += EMB[(size_t)b * 256 + p.tags[(s - 1) * 128 + b]];
    }
    gbar(barc, (++gen) * 256u);

    // ================= P3 =================
    f32x4 R, Z, N;
    const bool giact = (s < 256) && (w == 0 || w == 2);
    if (giact) {
      const int r0 = (blk >> 3) * 16, b0 = (blk & 7) * 16;
      const int kh = w >> 1;  // K half
      if (kh == 0) {
        const float4 b1 = *(const float4*)(p.bih + r0 + kg * 4);
        const float4 b2 = *(const float4*)(p.bih + 512 + r0 + kg * 4);
        const float4 b3 = *(const float4*)(p.bih + 1024 + r0 + kg * 4);
        R[0] = b1.x; R[1] = b1.y; R[2] = b1.z; R[3] = b1.w;
        Z[0] = b2.x; Z[1] = b2.y; Z[2] = b2.z; Z[3] = b2.w;
        N[0] = b3.x; N[1] = b3.y; N[2] = b3.z; N[3] = b3.w;
      } else {
        R = (f32x4){0.f, 0.f, 0.f, 0.f}; Z = R; N = R;
      }
      const u16* ArR = WIH16 + (size_t)(r0 + bq) * 512 + kh * 256 + kg * 8;
      const u16* ArZ = ArR + (size_t)512 * 512;
      const u16* ArN = ArR + (size_t)1024 * 512;
      const u16* Br = XB + (size_t)(b0 + bq) * 512 + kh * 256 + kg * 8;
#pragma unroll 4
      for (int kt = 0; kt < 8; ++kt) {
        const short8 bb = *(const short8*)(Br + kt * 32);
        R = MFMA16(*(const short8*)(ArR + kt * 32), bb, R);
        Z = MFMA16(*(const short8*)(ArZ + kt * 32), bb, Z);
        N = MFMA16(*(const short8*)(ArN + kt * 32), bb, N);
      }
      if (w == 2) {
#pragma unroll
        for (int r = 0; r < 4; ++r) {
          pr3[0][(kg * 4 + r) * 16 + bq] = R[r];
          pr3[1][(kg * 4 + r) * 16 + bq] = Z[r];
          pr3[2][(kg * 4 + r) * 16 + bq] = N[r];
        }
      }
    }
    __syncthreads();
    if (s < 256 && w == 0) {  // combine + gates + h_new
      const int r0 = (blk >> 3) * 16, b0 = (blk & 7) * 16;
      const int b = b0 + bq;
      const float4 gr4 = *(const float4*)(GHB + (size_t)b * 1536 + r0 + kg * 4);
      const float4 gz4 = *(const float4*)(GHB + (size_t)b * 1536 + 512 + r0 + kg * 4);
      const float4 gn4 = *(const float4*)(GHB + (size_t)b * 1536 + 1024 + r0 + kg * 4);
      const float grA[4] = {gr4.x, gr4.y, gr4.z, gr4.w};
      const float gzA[4] = {gz4.x, gz4.y, gz4.z, gz4.w};
      const float gnA[4] = {gn4.x, gn4.y, gn4.z, gn4.w};
      short4v h4 = *reinterpret_cast<short4v*>(HB + (size_t)b * 512 + r0 + kg * 4);
      short4v ho;
#pragma unroll
      for (int r = 0; r < 4; ++r) {
        const float Rv = R[r] + pr3[0][(kg * 4 + r) * 16 + bq];
        const float Zv = Z[r] + pr3[1][(kg * 4 + r) * 16 + bq];
        const float Nv = N[r] + pr3[2][(kg * 4 + r) * 16 + bq];
        const float rr = 1.f / (1.f + __expf(-(Rv + grA[r])));
        const float zz = 1.f / (1.f + __expf(-(Zv + gzA[r])));
        const float nn = tanhf(Nv + rr * gnA[r]);
        const float hold = bf2f((u16)h4[r]);
        ho[r] = (short)f2bf((1.f - zz) * nn + zz * hold);
      }
      *reinterpret_cast<short4v*>(HB + (size_t)b * 512 + r0 + kg * 4) = ho;
    }
    if (w == 1) {
      if (blk < 128) {
        if (s >= 1) {  // CRF-B
          const int kn0 = (blk >> 3) * 16, b0 = (blk & 7) * 16;
          const int b = b0 + bq;
          if (s == 1) {
            const float4 e4 = *(const float4*)(EMB + (size_t)b * 256 + kn0 + kg * 4);
            const float4 c4 = *(const float4*)(p.cs + kn0 + kg * 4);
            float4 o; o.x = c4.x + e4.x; o.y = c4.y + e4.y; o.z = c4.z + e4.z; o.w = c4.w + e4.w;
            *reinterpret_cast<float4*>(SRB + (size_t)b * 256 + kn0 + kg * 4) = o;
          } else {
            f32x4 acc = (f32x4){0.f, 0.f, 0.f, 0.f};
            const u16* Ar = WXT16 + (size_t)(kn0 + bq) * 256 + kg * 8;
            const u16* Br = PBu + (size_t)(b0 + bq) * 256 + kg * 8;
#pragma unroll 4
            for (int kt = 0; kt < 8; ++kt)
              acc = MFMA16(*(const short8*)(Ar + kt * 32), *(const short8*)(Br + kt * 32), acc);
            const float mf = MFB[b];
            const float4 e4 = *(const float4*)(EMB + (size_t)b * 256 + kn0 + kg * 4);
            float4 o;
            o.x = mf + __logf(acc[0]) + e4.x;
            o.y = mf + __logf(acc[1]) + e4.y;
            o.z = mf + __logf(acc[2]) + e4.z;
            o.w = mf + __logf(acc[3]) + e4.w;
            *reinterpret_cast<float4*>(SRB + (size_t)b * 256 + kn0 + kg * 4) = o;
          }
        }
      } else {
        if (s < 255) {  // stage e_{s+1}
          const int b = blk - 128;
          const int tok = p.tags[s * 128 + b];
          const float4 ev = *(const float4*)(p.emb + (size_t)tok * 256 + lane * 4);
          short4v ee;
          ee[0] = (short)f2bf(ev.x); ee[1] = (short)f2bf(ev.y);
          ee[2] = (short)f2bf(ev.z); ee[3] = (short)f2bf(ev.w);
          *reinterpret_cast<short4v*>(EB + (size_t)b * 256 + lane * 4) = ee;
        }
      }
    }
    gbar(barc, (++gen) * 256u);
  }
}

// ---------------- final: denominator + mean ----------------
__global__ void __launch_bounds__(128) kFinal(const float* __restrict__ ws,
                                              const float* __restrict__ ce,
                                              float* __restrict__ out) {
  __shared__ float acc[128];
  const int tid = threadIdx.x;  // 128
  const float* SRB = ws + F_SRB;
  float mx = -3.0e38f;
#pragma unroll 8
  for (int k = 0; k < 256; ++k) mx = fmaxf(mx, SRB[(size_t)tid * 256 + k] + ce[k]);
  float sm = 0.f;
#pragma unroll 8
  for (int k = 0; k < 256; ++k) sm += __expf(SRB[(size_t)tid * 256 + k] + ce[k] - mx);
  acc[tid] = ws[F_NSB + tid] + ws[F_NEB + tid] - (mx + __logf(sm));
  __syncthreads();
  if (tid < 64) {
    float v = acc[tid] + acc[tid + 64];
#pragma unroll
    for (int o = 32; o; o >>= 1) v += __shfl_xor(v, o);
    if (tid == 0) out[0] = v * (1.f / 128.f);
  }
}

extern "C" void kernel_launch(void* const* d_in, const int* in_sizes, int n_in,
                              void* d_out, int out_size, void* d_ws, size_t ws_size,
                              hipStream_t stream) {
  (void)in_sizes; (void)n_in; (void)out_size; (void)ws_size;
  const int* dec = (const int*)d_in[0];
  const int* tags = (const int*)d_in[1];
  const float* enc = (const float*)d_in[2];
  const float* emb = (const float*)d_in[3];
  const float* aW = (const float*)d_in[4];
  const float* ab = (const float*)d_in[5];
  const float* cW = (const float*)d_in[6];
  const float* cb = (const float*)d_in[7];
  const float* wih = (const float*)d_in[8];
  const float* whh = (const float*)d_in[9];
  const float* bih = (const float*)d_in[10];
  const float* bhh = (const float*)d_in[11];
  const float* oW = (const float*)d_in[12];
  const float* ob = (const float*)d_in[13];
  const float* cs = (const float*)d_in[14];
  const float* ce = (const float*)d_in[15];
  const float* ct = (const float*)d_in[16];
  float* ws = (float*)d_ws;
  float* out = (float*)d_out;

  kPrep<<<dim3(8192), dim3(256), 0, stream>>>(wih, whh, aW, oW, cW, ct, ws);
  kInit<<<dim3(256), dim3(256), 0, stream>>>(dec, tags, emb, cs, ce, ct, ws);
  kEncW<<<dim3(2048), dim3(256), 0, stream>>>(enc, cW, (u16*)d_ws);

  P9 p;
  p.dec = dec; p.tags = tags; p.emb = emb;
  p.ab = ab; p.cb = cb; p.bih = bih; p.bhh = bhh;
  p.ob = ob; p.cs = cs; p.ws = ws;
  void* args[] = { &p };
  hipLaunchCooperativeKernel((void*)maink, dim3(256), dim3(512), args, 0, stream);

  kFinal<<<dim3(1), dim3(128), 0, stream>>>(ws, ce, out);
}

// Round 7
// 8678.315 us; speedup vs baseline: 7.1064x; 2.7969x over previous
//
#include <hip/hip_runtime.h>

// Round 7: R6 with fixed asm operand order (offset:N before sc0 sc1).
// Fence-free coherent activations (sc0 sc1) + two-level gen-indexed barrier.
// Weights/encT stay in L2 (no L2 invalidation anywhere).
// 256 blocks x 512 threads, 3 barriers/step, same phase math as R5 (absmax 0).

typedef unsigned short u16;
typedef unsigned int u32;
typedef __attribute__((ext_vector_type(8))) short short8;
typedef __attribute__((ext_vector_type(4))) float f32x4;
typedef __attribute__((ext_vector_type(4))) u32 u32x4;
typedef __attribute__((ext_vector_type(2))) u32 u32x2;

#define MFMA16(a, b, c) __builtin_amdgcn_mfma_f32_16x16x32_bf16((a), (b), (c), 0, 0, 0)

// ---- ws layout ----
// u16 element offsets (base = ws)
#define U_ENC 0u           // encT bf16 [128 b][256 t][512 c]  (32MB)
#define U_WHH 16777216u    // [1536][512]
#define U_WIH 17563648u    // [1536][512]
#define U_WAW 18350080u    // [256][768]
#define U_WOW 18546688u    // [256][512]
#define U_WCE 18677760u    // [512][256]
#define U_WXT 18808832u    // [256][256]  expT[kn][k] = exp(trans[k][kn])
#define U_HB  18874368u    // h bf16 [128][512]
#define U_EB  18939904u    // e bf16 [128][256]
#define U_XB  18972672u    // x bf16 [128][512]
#define U_PB  19038208u    // p bf16 [128][256]
// f32 element offsets (base = ws)
#define F_LGB 9535488u     // logits f32 [128][256]
#define F_EMB 9568256u     // emissions f32 [128][256]
#define F_EPB 9601024u     // ep f32 [128][512]
#define F_GHB 9666560u     // gh f32 [128][1536]
#define F_SRB 9863168u     // CRF scores f32 [128][256]
#define F_MFB 9895936u     // [128]
#define F_NEB 9896064u     // [128]
#define F_NSB 9896192u     // [128]
#define F_BAR 9896448u     // u32 region: L1[771][16] stride-16 (197376) + REL[771]
#define BAR_N 198147u

__device__ __forceinline__ float bf2f(u16 u) { return __uint_as_float(((u32)u) << 16); }
__device__ __forceinline__ u16 f2bf(float f) {
  u32 u = __float_as_uint(f);
  return (u16)((u + 0x7FFFu + ((u >> 16) & 1u)) >> 16);
}
__device__ __forceinline__ u32 pk2(float a, float b) {
  return (u32)f2bf(a) | ((u32)f2bf(b) << 16);
}

// ---- coherent (sc0 sc1) load/store helpers ----
__device__ __forceinline__ float ldcg_f(const float* p) {
  float r;
  asm volatile("global_load_dword %0, %1, off sc0 sc1\n\ts_waitcnt vmcnt(0)"
               : "=v"(r) : "v"(p));
  return r;
}
__device__ __forceinline__ f32x4 ldcg_f4(const float* p) {
  f32x4 r;
  asm volatile("global_load_dwordx4 %0, %1, off sc0 sc1\n\ts_waitcnt vmcnt(0)"
               : "=v"(r) : "v"(p));
  return r;
}
__device__ __forceinline__ u32x2 ldcg_b8(const u16* p) {
  u32x2 r;
  asm volatile("global_load_dwordx2 %0, %1, off sc0 sc1\n\ts_waitcnt vmcnt(0)"
               : "=v"(r) : "v"(p));
  return r;
}
__device__ __forceinline__ void ldcg_f4x3(f32x4& a, f32x4& b, f32x4& c,
                                          const float* p0, const float* p1,
                                          const float* p2) {
  asm volatile(
      "global_load_dwordx4 %0, %3, off sc0 sc1\n\t"
      "global_load_dwordx4 %1, %4, off sc0 sc1\n\t"
      "global_load_dwordx4 %2, %5, off sc0 sc1\n\t"
      "s_waitcnt vmcnt(0)"
      : "=&v"(a), "=&v"(b), "=&v"(c)
      : "v"(p0), "v"(p1), "v"(p2));
}
__device__ __forceinline__ void ldcg8(u32x4 d[8], const u16* p) {
  asm volatile(
      "global_load_dwordx4 %0, %8, off sc0 sc1\n\t"
      "global_load_dwordx4 %1, %8, off offset:64 sc0 sc1\n\t"
      "global_load_dwordx4 %2, %8, off offset:128 sc0 sc1\n\t"
      "global_load_dwordx4 %3, %8, off offset:192 sc0 sc1\n\t"
      "global_load_dwordx4 %4, %8, off offset:256 sc0 sc1\n\t"
      "global_load_dwordx4 %5, %8, off offset:320 sc0 sc1\n\t"
      "global_load_dwordx4 %6, %8, off offset:384 sc0 sc1\n\t"
      "global_load_dwordx4 %7, %8, off offset:448 sc0 sc1\n\t"
      "s_waitcnt vmcnt(0)"
      : "=&v"(d[0]), "=&v"(d[1]), "=&v"(d[2]), "=&v"(d[3]),
        "=&v"(d[4]), "=&v"(d[5]), "=&v"(d[6]), "=&v"(d[7])
      : "v"(p));
}
__device__ __forceinline__ void ldcg16(u32x4 d[16], const u16* p) {
  asm volatile(
      "global_load_dwordx4 %0, %16, off sc0 sc1\n\t"
      "global_load_dwordx4 %1, %16, off offset:64 sc0 sc1\n\t"
      "global_load_dwordx4 %2, %16, off offset:128 sc0 sc1\n\t"
      "global_load_dwordx4 %3, %16, off offset:192 sc0 sc1\n\t"
      "global_load_dwordx4 %4, %16, off offset:256 sc0 sc1\n\t"
      "global_load_dwordx4 %5, %16, off offset:320 sc0 sc1\n\t"
      "global_load_dwordx4 %6, %16, off offset:384 sc0 sc1\n\t"
      "global_load_dwordx4 %7, %16, off offset:448 sc0 sc1\n\t"
      "global_load_dwordx4 %8, %16, off offset:512 sc0 sc1\n\t"
      "global_load_dwordx4 %9, %16, off offset:576 sc0 sc1\n\t"
      "global_load_dwordx4 %10, %16, off offset:640 sc0 sc1\n\t"
      "global_load_dwordx4 %11, %16, off offset:704 sc0 sc1\n\t"
      "global_load_dwordx4 %12, %16, off offset:768 sc0 sc1\n\t"
      "global_load_dwordx4 %13, %16, off offset:832 sc0 sc1\n\t"
      "global_load_dwordx4 %14, %16, off offset:896 sc0 sc1\n\t"
      "global_load_dwordx4 %15, %16, off offset:960 sc0 sc1\n\t"
      "s_waitcnt vmcnt(0)"
      : "=&v"(d[0]), "=&v"(d[1]), "=&v"(d[2]), "=&v"(d[3]),
        "=&v"(d[4]), "=&v"(d[5]), "=&v"(d[6]), "=&v"(d[7]),
        "=&v"(d[8]), "=&v"(d[9]), "=&v"(d[10]), "=&v"(d[11]),
        "=&v"(d[12]), "=&v"(d[13]), "=&v"(d[14]), "=&v"(d[15])
      : "v"(p));
}
__device__ __forceinline__ void stcg_f(float* p, float v) {
  asm volatile("global_store_dword %0, %1, off sc0 sc1" ::"v"(p), "v"(v) : "memory");
}
__device__ __forceinline__ void stcg_f4(float* p, f32x4 v) {
  asm volatile("global_store_dwordx4 %0, %1, off sc0 sc1" ::"v"(p), "v"(v) : "memory");
}
__device__ __forceinline__ void stcg_b8(u16* p, u32x2 v) {
  asm volatile("global_store_dwordx2 %0, %1, off sc0 sc1" ::"v"(p), "v"(v) : "memory");
}

// ---- two-level generation-indexed grid barrier (no fences, no L2 flush) ----
__device__ __forceinline__ void gbar2(u32* bar, u32 gen, int grp) {
  __syncthreads();  // drains each wave's vmcnt -> write-through stores visible
  if (threadIdx.x == 0) {
    u32* l1 = bar + ((size_t)gen * 16u + (u32)grp) * 16u;
    u32* rel = bar + 197376u + gen;
    const u32 old = __hip_atomic_fetch_add(l1, 1u, __ATOMIC_RELAXED,
                                           __HIP_MEMORY_SCOPE_AGENT);
    if (old == 15u)
      __hip_atomic_fetch_add(rel, 1u, __ATOMIC_RELAXED, __HIP_MEMORY_SCOPE_AGENT);
    while (__hip_atomic_load(rel, __ATOMIC_RELAXED, __HIP_MEMORY_SCOPE_AGENT) < 16u) {}
  }
  __syncthreads();
}

// ---------------- weight convert to bf16 (2,097,152 elems) ----------------
__global__ void __launch_bounds__(256) kPrep(const float* __restrict__ wih,
                                             const float* __restrict__ whh,
                                             const float* __restrict__ aW,
                                             const float* __restrict__ oW,
                                             const float* __restrict__ cW,
                                             const float* __restrict__ ct,
                                             float* __restrict__ ws) {
  u16* W = (u16*)ws;
  const u32 i = blockIdx.x * 256 + threadIdx.x;
  if (i < 786432u) {
    W[U_WHH + i] = f2bf(whh[i]);
  } else if (i < 1572864u) {
    const u32 j = i - 786432u;
    W[U_WIH + j] = f2bf(wih[j]);
  } else if (i < 1769472u) {
    const u32 j = i - 1572864u;
    W[U_WAW + j] = f2bf(aW[j]);
  } else if (i < 1900544u) {
    const u32 j = i - 1769472u;
    W[U_WOW + j] = f2bf(oW[j]);
  } else if (i < 2031616u) {
    const u32 j = i - 1900544u;
    W[U_WCE + j] = f2bf(cW[(size_t)(j >> 8) * 1280 + (j & 255u)]);
  } else {
    const u32 j = i - 2031616u;
    const u32 kn = j >> 8, k = j & 255u;
    W[U_WXT + j] = f2bf(__expf(ct[k * 256u + kn]));
  }
}

// ---------------- init: zero h, stage e0, numerator, barrier counters ----------------
__global__ void __launch_bounds__(256) kInit(const int* __restrict__ dec,
                                             const int* __restrict__ tags,
                                             const float* __restrict__ emb,
                                             const float* __restrict__ cs,
                                             const float* __restrict__ ce,
                                             const float* __restrict__ ct,
                                             float* __restrict__ ws) {
  const u32 idx = blockIdx.x * 256 + threadIdx.x;  // 65536
  u16* ENC = (u16*)ws;
  u16* HB = ENC + U_HB;
  u16* EB = ENC + U_EB;
  if (idx < 32768u) {
    ((u32*)HB)[idx] = 0u;
    const int b = idx >> 8, j = idx & 255;
    EB[idx] = f2bf(emb[(size_t)dec[b] * 256 + j]);
  }
  if (idx < 128u) {
    int prev = tags[idx];
    float a = cs[prev];
    for (int t = 1; t < 256; ++t) {
      const int cur = tags[t * 128 + idx];
      a += ct[prev * 256 + cur];
      prev = cur;
    }
    ws[F_NSB + idx] = a + ce[prev];
    ws[F_NEB + idx] = 0.f;
  }
  u32* bar = (u32*)(ws + F_BAR);
  if (idx < 49537u) {
#pragma unroll
    for (int j = 0; j < 4; ++j) {
      const u32 k = idx * 4u + (u32)j;
      if (k < BAR_N) bar[k] = 0u;
    }
  }
}

// ---------------- encT[b][t][c] = sum_j enc[t,b,j] * comb_W[c, 256+j] (bf16) ----------------
__global__ void __launch_bounds__(256) kEncW(const float* __restrict__ enc,
                                             const float* __restrict__ cW,
                                             u16* __restrict__ encT) {
  __shared__ float wL[64 * 64];
  const int t = blockIdx.x >> 3, cblk = blockIdx.x & 7;
  const int tid = threadIdx.x;
  const int bg = tid & 31;
  const int cg = tid >> 5;
  float acc[4][8];
#pragma unroll
  for (int i = 0; i < 4; ++i)
#pragma unroll
    for (int c = 0; c < 8; ++c) acc[i][c] = 0.f;
  const float* encB = enc + (size_t)t * (128 * 1024);
  for (int jt = 0; jt < 16; ++jt) {
    const int j0 = jt * 64;
    __syncthreads();
    for (int i = tid; i < 4096; i += 256) {
      const int cc = i >> 6, jj = i & 63;
      wL[cc * 64 + jj] = cW[(size_t)(cblk * 64 + cc) * 1280 + 256 + j0 + jj];
    }
    __syncthreads();
    for (int jj = 0; jj < 64; ++jj) {
      const float e0 = encB[(bg * 4 + 0) * 1024 + j0 + jj];
      const float e1 = encB[(bg * 4 + 1) * 1024 + j0 + jj];
      const float e2 = encB[(bg * 4 + 2) * 1024 + j0 + jj];
      const float e3 = encB[(bg * 4 + 3) * 1024 + j0 + jj];
#pragma unroll
      for (int c = 0; c < 8; ++c) {
        const float wv = wL[(cg * 8 + c) * 64 + jj];
        acc[0][c] = fmaf(e0, wv, acc[0][c]);
        acc[1][c] = fmaf(e1, wv, acc[1][c]);
        acc[2][c] = fmaf(e2, wv, acc[2][c]);
        acc[3][c] = fmaf(e3, wv, acc[3][c]);
      }
    }
  }
#pragma unroll
  for (int i = 0; i < 4; ++i)
    for (int c = 0; c < 8; ++c) {
      const int b = bg * 4 + i, cc = cblk * 64 + cg * 8 + c;
      encT[(size_t)b * 131072u + (size_t)t * 512u + cc] = f2bf(acc[i][c]);
    }
}

struct P9 {
  const int* dec; const int* tags; const float* emb;
  const float* ab; const float* cb; const float* bih; const float* bhh;
  const float* ob; const float* cs;
  float* ws;
};

// ---------------- main cooperative kernel ----------------
__global__ void __launch_bounds__(512, 2) maink(P9 p) {
  float* const ws = p.ws;
  u16* const ENC = (u16*)ws;
  const u16* const WHH16 = ENC + U_WHH;
  const u16* const WIH16 = ENC + U_WIH;
  const u16* const WAW16 = ENC + U_WAW;
  const u16* const WOW16 = ENC + U_WOW;
  const u16* const WCE16 = ENC + U_WCE;
  const u16* const WXT16 = ENC + U_WXT;
  u16* const HB = ENC + U_HB;
  u16* const EB = ENC + U_EB;
  u16* const XB = ENC + U_XB;
  u16* const PBu = ENC + U_PB;
  float* const LGB = ws + F_LGB;
  float* const EMB = ws + F_EMB;
  float* const EPB = ws + F_EPB;
  float* const GHB = ws + F_GHB;
  float* const SRB = ws + F_SRB;
  float* const MFB = ws + F_MFB;
  float* const NEB = ws + F_NEB;
  u32* const bar = (u32*)(ws + F_BAR);

  __shared__ float prL[256];
  __shared__ float pacc[4][256];
  __shared__ float red[16];
  __shared__ float pr3[3][256];

  const int tid = threadIdx.x;
  const int w = tid >> 6, lane = tid & 63;
  const int bq = lane & 15, kg = lane >> 4;
  const int blk = blockIdx.x;
  const int grp = blk >> 4;
  u32 gen = 0;

  for (int s = 0; s <= 256; ++s) {
    // ================= P1 =================
    if (w < 3) {
      if (s < 256) {  // gh: t = w*256+blk in [0,768)
        const int t = w * 256 + blk;
        const int r0 = (t >> 3) * 16, b0 = (t & 7) * 16;
        f32x4 acc;
        const float4 bs = *(const float4*)(p.bhh + r0 + kg * 4);
        acc[0] = bs.x; acc[1] = bs.y; acc[2] = bs.z; acc[3] = bs.w;
        u32x4 Bf[16];
        ldcg16(Bf, HB + (size_t)(b0 + bq) * 512 + kg * 8);
        const u16* Ar = WHH16 + (size_t)(r0 + bq) * 512 + kg * 8;
#pragma unroll
        for (int kt = 0; kt < 16; ++kt)
          acc = MFMA16(*(const short8*)(Ar + kt * 32),
                       __builtin_bit_cast(short8, Bf[kt]), acc);
        stcg_f4(GHB + (size_t)(b0 + bq) * 1536 + r0 + kg * 4, acc);
      }
    } else if (w == 3) {
      if (blk < 128) {
        if (s < 256) {  // attn logits, K=768
          const int r0 = (blk >> 3) * 16, b0 = (blk & 7) * 16;
          f32x4 acc;
          const float4 bs = *(const float4*)(p.ab + r0 + kg * 4);
          acc[0] = bs.x; acc[1] = bs.y; acc[2] = bs.z; acc[3] = bs.w;
          u32x4 Ef[8], Hf[16];
          ldcg8(Ef, EB + (size_t)(b0 + bq) * 256 + kg * 8);
          ldcg16(Hf, HB + (size_t)(b0 + bq) * 512 + kg * 8);
          const u16* Ar = WAW16 + (size_t)(r0 + bq) * 768 + kg * 8;
#pragma unroll
          for (int kt = 0; kt < 8; ++kt)
            acc = MFMA16(*(const short8*)(Ar + kt * 32),
                         __builtin_bit_cast(short8, Ef[kt]), acc);
#pragma unroll
          for (int kt = 0; kt < 16; ++kt)
            acc = MFMA16(*(const short8*)(Ar + 256 + kt * 32),
                         __builtin_bit_cast(short8, Hf[kt]), acc);
          stcg_f4(LGB + (size_t)(b0 + bq) * 256 + r0 + kg * 4, acc);
        }
      } else {
        if (s >= 1) {  // em_{s-1} from current h
          const int t2 = blk - 128;
          const int r0 = (t2 >> 3) * 16, b0 = (t2 & 7) * 16;
          f32x4 acc;
          const float4 bs = *(const float4*)(p.ob + r0 + kg * 4);
          acc[0] = bs.x; acc[1] = bs.y; acc[2] = bs.z; acc[3] = bs.w;
          u32x4 Hf[16];
          ldcg16(Hf, HB + (size_t)(b0 + bq) * 512 + kg * 8);
          const u16* Ar = WOW16 + (size_t)(r0 + bq) * 512 + kg * 8;
#pragma unroll
          for (int kt = 0; kt < 16; ++kt)
            acc = MFMA16(*(const short8*)(Ar + kt * 32),
                         __builtin_bit_cast(short8, Hf[kt]), acc);
          stcg_f4(EMB + (size_t)(b0 + bq) * 256 + r0 + kg * 4, acc);
        }
      }
    } else if (w == 4) {
      if (s < 256) {  // ep = cb + cWe @ e
        const int r0 = (blk >> 3) * 16, b0 = (blk & 7) * 16;
        f32x4 acc;
        const float4 bs = *(const float4*)(p.cb + r0 + kg * 4);
        acc[0] = bs.x; acc[1] = bs.y; acc[2] = bs.z; acc[3] = bs.w;
        u32x4 Ef[8];
        ldcg8(Ef, EB + (size_t)(b0 + bq) * 256 + kg * 8);
        const u16* Ar = WCE16 + (size_t)(r0 + bq) * 256 + kg * 8;
#pragma unroll
        for (int kt = 0; kt < 8; ++kt)
          acc = MFMA16(*(const short8*)(Ar + kt * 32),
                       __builtin_bit_cast(short8, Ef[kt]), acc);
        stcg_f4(EPB + (size_t)(b0 + bq) * 512 + r0 + kg * 4, acc);
      }
    } else if (w == 5) {
      if (blk < 128 && s >= 2) {  // CRF-A
        const int b = blk;
        const f32x4 sv = ldcg_f4(SRB + (size_t)b * 256 + lane * 4);
        float mx = fmaxf(fmaxf(sv[0], sv[1]), fmaxf(sv[2], sv[3]));
#pragma unroll
        for (int o = 32; o; o >>= 1) mx = fmaxf(mx, __shfl_xor(mx, o));
        u32x2 pv;
        pv[0] = pk2(__expf(sv[0] - mx), __expf(sv[1] - mx));
        pv[1] = pk2(__expf(sv[2] - mx), __expf(sv[3] - mx));
        stcg_b8(PBu + (size_t)b * 256 + lane * 4, pv);
        if (lane == 0) stcg_f(MFB + b, mx);
      }
    }
    gbar2(bar, gen++, grp);

    // ================= P2 (256 blocks: b = blk&127, c-half = blk>>7) =================
    {
      const int b = blk & 127, chalf = blk >> 7;
      if (s < 256) {
        float v = -3.0e38f;
        if (tid < 256) v = ldcg_f(LGB + (size_t)b * 256 + tid);
        float m = v;
#pragma unroll
        for (int o = 32; o; o >>= 1) m = fmaxf(m, __shfl_xor(m, o));
        if (lane == 0) red[w] = m;
        __syncthreads();
        float mB = red[0];
#pragma unroll
        for (int q = 1; q < 8; ++q) mB = fmaxf(mB, red[q]);
        float e = 0.f;
        if (tid < 256) { e = __expf(v - mB); prL[tid] = e; }
        float sacc = e;
#pragma unroll
        for (int o = 32; o; o >>= 1) sacc += __shfl_xor(sacc, o);
        if (lane == 0) red[8 + w] = sacc;
        __syncthreads();
        float sum = red[8];
#pragma unroll
        for (int q = 1; q < 8; ++q) sum += red[8 + q];
        const float inv = 1.f / sum;
        // nt-stream this block's c-half of encT (keeps weights in L2)
        const int tq = tid >> 7, cp = tid & 127;
        const int c0l = cp * 2;
        const u16* base = ENC + (size_t)b * 131072u + (size_t)(tq * 64) * 512u +
                          (chalf * 256 + c0l);
        const float* prh = prL + tq * 64;
        float a0 = 0.f, a1 = 0.f;
#pragma unroll 8
        for (int t = 0; t < 64; ++t) {
          const float prt = prh[t];
          const u32 vv = __builtin_nontemporal_load((const u32*)(base + (size_t)t * 512));
          a0 = fmaf(prt, bf2f((u16)(vv & 0xffffu)), a0);
          a1 = fmaf(prt, bf2f((u16)(vv >> 16)), a1);
        }
        pacc[tq][c0l] = a0;
        pacc[tq][c0l + 1] = a1;
        __syncthreads();
        if (tid < 64) {
          const int cl = tid * 4;
          const f32x4 ep4 = ldcg_f4(EPB + (size_t)b * 512 + chalf * 256 + cl);
          float xv[4];
#pragma unroll
          for (int r = 0; r < 4; ++r)
            xv[r] = fmaxf(ep4[r] + (pacc[0][cl + r] + pacc[1][cl + r] +
                                    pacc[2][cl + r] + pacc[3][cl + r]) * inv, 0.f);
          u32x2 xo;
          xo[0] = pk2(xv[0], xv[1]);
          xo[1] = pk2(xv[2], xv[3]);
          stcg_b8(XB + (size_t)b * 512 + chalf * 256 + cl, xo);
        }
      }
      if (chalf == 0 && s >= 1 && tid == 0) {
        const int tg = p.tags[(s - 1) * 128 + b];
        const float em = ldcg_f(EMB + (size_t)b * 256 + tg);
        const float ne = ldcg_f(NEB + b);
        stcg_f(NEB + b, ne + em);
      }
    }
    gbar2(bar, gen++, grp);

    // ================= P3 =================
    f32x4 R, Z, N;
    const bool giact = (s < 256) && (w == 0 || w == 2);
    if (giact) {
      const int r0 = (blk >> 3) * 16, b0 = (blk & 7) * 16;
      const int kh = w >> 1;
      if (kh == 0) {
        const float4 b1 = *(const float4*)(p.bih + r0 + kg * 4);
        const float4 b2 = *(const float4*)(p.bih + 512 + r0 + kg * 4);
        const float4 b3 = *(const float4*)(p.bih + 1024 + r0 + kg * 4);
        R[0] = b1.x; R[1] = b1.y; R[2] = b1.z; R[3] = b1.w;
        Z[0] = b2.x; Z[1] = b2.y; Z[2] = b2.z; Z[3] = b2.w;
        N[0] = b3.x; N[1] = b3.y; N[2] = b3.z; N[3] = b3.w;
      } else {
        R = (f32x4){0.f, 0.f, 0.f, 0.f}; Z = R; N = R;
      }
      u32x4 Xf[8];
      ldcg8(Xf, XB + (size_t)(b0 + bq) * 512 + kh * 256 + kg * 8);
      const u16* ArR = WIH16 + (size_t)(r0 + bq) * 512 + kh * 256 + kg * 8;
      const u16* ArZ = ArR + (size_t)512 * 512;
      const u16* ArN = ArR + (size_t)1024 * 512;
#pragma unroll
      for (int kt = 0; kt < 8; ++kt) {
        const short8 bb = __builtin_bit_cast(short8, Xf[kt]);
        R = MFMA16(*(const short8*)(ArR + kt * 32), bb, R);
        Z = MFMA16(*(const short8*)(ArZ + kt * 32), bb, Z);
        N = MFMA16(*(const short8*)(ArN + kt * 32), bb, N);
      }
      if (w == 2) {
#pragma unroll
        for (int r = 0; r < 4; ++r) {
          pr3[0][(kg * 4 + r) * 16 + bq] = R[r];
          pr3[1][(kg * 4 + r) * 16 + bq] = Z[r];
          pr3[2][(kg * 4 + r) * 16 + bq] = N[r];
        }
      }
    }
    __syncthreads();
    if (s < 256 && w == 0) {  // combine + gates + h_new
      const int r0 = (blk >> 3) * 16, b0 = (blk & 7) * 16;
      const int b = b0 + bq;
      f32x4 gr4, gz4, gn4;
      ldcg_f4x3(gr4, gz4, gn4,
                GHB + (size_t)b * 1536 + r0 + kg * 4,
                GHB + (size_t)b * 1536 + 512 + r0 + kg * 4,
                GHB + (size_t)b * 1536 + 1024 + r0 + kg * 4);
      const u32x2 h4 = ldcg_b8(HB + (size_t)b * 512 + r0 + kg * 4);
      const float hold[4] = {bf2f((u16)(h4[0] & 0xffffu)), bf2f((u16)(h4[0] >> 16)),
                             bf2f((u16)(h4[1] & 0xffffu)), bf2f((u16)(h4[1] >> 16))};
      float hn[4];
#pragma unroll
      for (int r = 0; r < 4; ++r) {
        const float Rv = R[r] + pr3[0][(kg * 4 + r) * 16 + bq];
        const float Zv = Z[r] + pr3[1][(kg * 4 + r) * 16 + bq];
        const float Nv = N[r] + pr3[2][(kg * 4 + r) * 16 + bq];
        const float rr = 1.f / (1.f + __expf(-(Rv + gr4[r])));
        const float zz = 1.f / (1.f + __expf(-(Zv + gz4[r])));
        const float nn = tanhf(Nv + rr * gn4[r]);
        hn[r] = (1.f - zz) * nn + zz * hold[r];
      }
      u32x2 ho;
      ho[0] = pk2(hn[0], hn[1]);
      ho[1] = pk2(hn[2], hn[3]);
      stcg_b8(HB + (size_t)b * 512 + r0 + kg * 4, ho);
    }
    if (w == 1) {
      if (blk < 128) {
        if (s >= 1) {  // CRF-B
          const int kn0 = (blk >> 3) * 16, b0 = (blk & 7) * 16;
          const int b = b0 + bq;
          if (s == 1) {
            const f32x4 e4 = ldcg_f4(EMB + (size_t)b * 256 + kn0 + kg * 4);
            const float4 c4 = *(const float4*)(p.cs + kn0 + kg * 4);
            f32x4 o;
            o[0] = c4.x + e4[0]; o[1] = c4.y + e4[1];
            o[2] = c4.z + e4[2]; o[3] = c4.w + e4[3];
            stcg_f4(SRB + (size_t)b * 256 + kn0 + kg * 4, o);
          } else {
            f32x4 acc = (f32x4){0.f, 0.f, 0.f, 0.f};
            u32x4 Pf[8];
            ldcg8(Pf, PBu + (size_t)(b0 + bq) * 256 + kg * 8);
            const u16* Ar = WXT16 + (size_t)(kn0 + bq) * 256 + kg * 8;
#pragma unroll
            for (int kt = 0; kt < 8; ++kt)
              acc = MFMA16(*(const short8*)(Ar + kt * 32),
                           __builtin_bit_cast(short8, Pf[kt]), acc);
            const float mf = ldcg_f(MFB + b);
            const f32x4 e4 = ldcg_f4(EMB + (size_t)b * 256 + kn0 + kg * 4);
            f32x4 o;
            o[0] = mf + __logf(acc[0]) + e4[0];
            o[1] = mf + __logf(acc[1]) + e4[1];
            o[2] = mf + __logf(acc[2]) + e4[2];
            o[3] = mf + __logf(acc[3]) + e4[3];
            stcg_f4(SRB + (size_t)b * 256 + kn0 + kg * 4, o);
          }
        }
      } else {
        if (s < 255) {  // stage e_{s+1}
          const int b = blk - 128;
          const int tok = p.tags[s * 128 + b];
          const float4 ev = *(const float4*)(p.emb + (size_t)tok * 256 + lane * 4);
          u32x2 ee;
          ee[0] = pk2(ev.x, ev.y);
          ee[1] = pk2(ev.z, ev.w);
          stcg_b8(EB + (size_t)b * 256 + lane * 4, ee);
        }
      }
    }
    gbar2(bar, gen++, grp);
  }
}

// ---------------- final: denominator + mean ----------------
__global__ void __launch_bounds__(128) kFinal(const float* __restrict__ ws,
                                              const float* __restrict__ ce,
                                              float* __restrict__ out) {
  __shared__ float acc[128];
  const int tid = threadIdx.x;  // 128
  const float* SRB = ws + F_SRB;
  float mx = -3.0e38f;
#pragma unroll 8
  for (int k = 0; k < 256; ++k) mx = fmaxf(mx, SRB[(size_t)tid * 256 + k] + ce[k]);
  float sm = 0.f;
#pragma unroll 8
  for (int k = 0; k < 256; ++k) sm += __expf(SRB[(size_t)tid * 256 + k] + ce[k] - mx);
  acc[tid] = ws[F_NSB + tid] + ws[F_NEB + tid] - (mx + __logf(sm));
  __syncthreads();
  if (tid < 64) {
    float v = acc[tid] + acc[tid + 64];
#pragma unroll
    for (int o = 32; o; o >>= 1) v += __shfl_xor(v, o);
    if (tid == 0) out[0] = v * (1.f / 128.f);
  }
}

extern "C" void kernel_launch(void* const* d_in, const int* in_sizes, int n_in,
                              void* d_out, int out_size, void* d_ws, size_t ws_size,
                              hipStream_t stream) {
  (void)in_sizes; (void)n_in; (void)out_size; (void)ws_size;
  const int* dec = (const int*)d_in[0];
  const int* tags = (const int*)d_in[1];
  const float* enc = (const float*)d_in[2];
  const float* emb = (const float*)d_in[3];
  const float* aW = (const float*)d_in[4];
  const float* ab = (const float*)d_in[5];
  const float* cW = (const float*)d_in[6];
  const float* cb = (const float*)d_in[7];
  const float* wih = (const float*)d_in[8];
  const float* whh = (const float*)d_in[9];
  const float* bih = (const float*)d_in[10];
  const float* bhh = (const float*)d_in[11];
  const float* oW = (const float*)d_in[12];
  const float* ob = (const float*)d_in[13];
  const float* cs = (const float*)d_in[14];
  const float* ce = (const float*)d_in[15];
  const float* ct = (const float*)d_in[16];
  float* ws = (float*)d_ws;
  float* out = (float*)d_out;

  kPrep<<<dim3(8192), dim3(256), 0, stream>>>(wih, whh, aW, oW, cW, ct, ws);
  kInit<<<dim3(256), dim3(256), 0, stream>>>(dec, tags, emb, cs, ce, ct, ws);
  kEncW<<<dim3(2048), dim3(256), 0, stream>>>(enc, cW, (u16*)d_ws);

  P9 p;
  p.dec = dec; p.tags = tags; p.emb = emb;
  p.ab = ab; p.cb = cb; p.bih = bih; p.bhh = bhh;
  p.ob = ob; p.cs = cs; p.ws = ws;
  void* args[] = { &p };
  hipLaunchCooperativeKernel((void*)maink, dim3(256), dim3(512), args, 0, stream);

  kFinal<<<dim3(1), dim3(128), 0, stream>>>(ws, ce, out);
}